// Round 1
// baseline (837.499 us; speedup 1.0000x reference)
//
#include <hip/hip_runtime.h>
#include <math.h>

#define BATCH 4
#define CTX   2048
#define EMB   1024
#define HEAD  128

// ---------------------------------------------------------------------------
// Kernel 1: QKV projection.  X[8192,1024] @ W[1024,128] -> {q,k,v}[8192,128]
// BM=64, BN=128, BK=16, 256 threads, 4x8 micro-tile per thread.
// grid = (128, 3)  (y selects Wq/Wk/Wv)
// ---------------------------------------------------------------------------
__global__ __launch_bounds__(256)
void qkv_proj_kernel(const float* __restrict__ x,
                     const float* __restrict__ Wq,
                     const float* __restrict__ Wk,
                     const float* __restrict__ Wv,
                     float* __restrict__ qo,
                     float* __restrict__ ko,
                     float* __restrict__ vo) {
    const int mt   = blockIdx.x;          // row tile (64 rows)
    const int wsel = blockIdx.y;          // 0:q 1:k 2:v
    const float* W = (wsel == 0) ? Wq : (wsel == 1) ? Wk : Wv;
    float* outp    = (wsel == 0) ? qo : (wsel == 1) ? ko : vo;
    const int tid  = threadIdx.x;

    // Xs transposed [kk][row]; pads keep 16B alignment and break write conflicts
    __shared__ float Xs[16][68];
    __shared__ float Ws[16][132];

    const int tr = tid >> 4;   // 0..15 -> rows 4*tr..4*tr+3
    const int tc = tid & 15;   // 0..15 -> cols 8*tc..8*tc+7

    float acc[4][8];
    #pragma unroll
    for (int i = 0; i < 4; ++i)
        #pragma unroll
        for (int j = 0; j < 8; ++j) acc[i][j] = 0.f;

    for (int kt = 0; kt < EMB; kt += 16) {
        __syncthreads();
        {   // X tile 64x16: one float4 per thread, stored transposed
            const int row = tid >> 2;
            const int c4  = tid & 3;
            const float4 xv = *(const float4*)&x[(size_t)(mt*64 + row)*EMB + kt + c4*4];
            Xs[c4*4+0][row] = xv.x;
            Xs[c4*4+1][row] = xv.y;
            Xs[c4*4+2][row] = xv.z;
            Xs[c4*4+3][row] = xv.w;
        }
        #pragma unroll
        for (int i = 0; i < 2; ++i) {   // W tile 16x128: two float4 per thread
            const int f  = tid + 256*i;
            const int kk = f >> 5;
            const int c4 = f & 31;
            *(float4*)&Ws[kk][c4*4] = *(const float4*)&W[(size_t)(kt+kk)*HEAD + c4*4];
        }
        __syncthreads();
        #pragma unroll
        for (int kk = 0; kk < 16; ++kk) {
            const float4 a4 = *(const float4*)&Xs[kk][4*tr];
            const float4 b0 = *(const float4*)&Ws[kk][8*tc];
            const float4 b1 = *(const float4*)&Ws[kk][8*tc+4];
            const float a[4]  = {a4.x, a4.y, a4.z, a4.w};
            const float bb[8] = {b0.x, b0.y, b0.z, b0.w, b1.x, b1.y, b1.z, b1.w};
            #pragma unroll
            for (int i = 0; i < 4; ++i)
                #pragma unroll
                for (int j = 0; j < 8; ++j)
                    acc[i][j] = fmaf(a[i], bb[j], acc[i][j]);
        }
    }
    #pragma unroll
    for (int i = 0; i < 4; ++i) {
        const size_t row = (size_t)(mt*64 + 4*tr + i);
        float4 o0 = make_float4(acc[i][0], acc[i][1], acc[i][2], acc[i][3]);
        float4 o1 = make_float4(acc[i][4], acc[i][5], acc[i][6], acc[i][7]);
        *(float4*)&outp[row*HEAD + 8*tc]     = o0;
        *(float4*)&outp[row*HEAD + 8*tc + 4] = o1;
    }
}

// ---------------------------------------------------------------------------
// Kernel 2: flash-style causal attention (fp32).
// One block per (batch, 32-row q tile).  grid = (64, 4), 256 threads.
// K/V staged in LDS 32x128 per tile; online softmax (m,l per row in LDS);
// O accumulator in registers: 2 rows x 8 cols per thread.
// ---------------------------------------------------------------------------
__global__ __launch_bounds__(256)
void attn_kernel(const float* __restrict__ q,
                 const float* __restrict__ k,
                 const float* __restrict__ v,
                 float* __restrict__ out) {
    const int qt  = blockIdx.x;   // 0..63
    const int b   = blockIdx.y;   // 0..3
    const int tid = threadIdx.x;

    __shared__ float Qs[32][128];
    __shared__ float Ks[32][128];
    __shared__ float Vs[32][132];   // padded (132*4B = 33*16B, keeps float4 alignment)
    __shared__ float Ss[32][36];    // padded
    __shared__ float mrow[32], lrow[32], arow[32];

    const float scale = 0.08838834764831845f;  // 1/sqrt(128)

    // load Q tile, pre-scaled
    #pragma unroll
    for (int i = 0; i < 4; ++i) {
        const int f  = tid + 256*i;
        const int r  = f >> 5;
        const int c4 = (f & 31) * 4;
        float4 t = *(const float4*)&q[((size_t)(b*CTX) + qt*32 + r)*HEAD + c4];
        t.x *= scale; t.y *= scale; t.z *= scale; t.w *= scale;
        *(float4*)&Qs[r][c4] = t;
    }
    if (tid < 32) { mrow[tid] = -3.0e38f; lrow[tid] = 0.f; }

    float o[2][8];
    #pragma unroll
    for (int i = 0; i < 2; ++i)
        #pragma unroll
        for (int j = 0; j < 8; ++j) o[i][j] = 0.f;

    const int rq = tid >> 4;   // score/O rows 2*rq, 2*rq+1
    const int cq = tid & 15;   // score cols 2*cq,2*cq+1 ; O cols 8*cq..8*cq+7

    for (int jt = 0; jt <= qt; ++jt) {
        __syncthreads();   // prev PV done / Qs+init ready (first iter)
        #pragma unroll
        for (int i = 0; i < 4; ++i) {   // K/V tiles 32x128
            const int f  = tid + 256*i;
            const int r  = f >> 5;
            const int c4 = (f & 31) * 4;
            const size_t g = ((size_t)(b*CTX) + jt*32 + r)*HEAD + c4;
            *(float4*)&Ks[r][c4] = *(const float4*)&k[g];
            *(float4*)&Vs[r][c4] = *(const float4*)&v[g];
        }
        __syncthreads();

        // S = Qs @ Ks^T, 2x2 per thread
        {
            float s00 = 0.f, s01 = 0.f, s10 = 0.f, s11 = 0.f;
            #pragma unroll
            for (int h = 0; h < HEAD; h += 4) {
                const float4 q0 = *(const float4*)&Qs[2*rq+0][h];
                const float4 q1 = *(const float4*)&Qs[2*rq+1][h];
                const float4 k0 = *(const float4*)&Ks[2*cq+0][h];
                const float4 k1 = *(const float4*)&Ks[2*cq+1][h];
                s00 += q0.x*k0.x + q0.y*k0.y + q0.z*k0.z + q0.w*k0.w;
                s01 += q0.x*k1.x + q0.y*k1.y + q0.z*k1.z + q0.w*k1.w;
                s10 += q1.x*k0.x + q1.y*k0.y + q1.z*k0.z + q1.w*k0.w;
                s11 += q1.x*k1.x + q1.y*k1.y + q1.z*k1.z + q1.w*k1.w;
            }
            if (jt == qt) {   // causal mask inside diagonal tile
                if (2*cq+0 > 2*rq+0) s00 = -1.0e30f;
                if (2*cq+1 > 2*rq+0) s01 = -1.0e30f;
                if (2*cq+0 > 2*rq+1) s10 = -1.0e30f;
                if (2*cq+1 > 2*rq+1) s11 = -1.0e30f;
            }
            Ss[2*rq+0][2*cq+0] = s00;
            Ss[2*rq+0][2*cq+1] = s01;
            Ss[2*rq+1][2*cq+0] = s10;
            Ss[2*rq+1][2*cq+1] = s11;
        }
        __syncthreads();

        // online softmax update: 8 threads per row, 4 entries each
        {
            const int row = tid >> 3;
            const int j0  = (tid & 7) * 4;
            float4 s4 = *(const float4*)&Ss[row][j0];
            float lm = fmaxf(fmaxf(s4.x, s4.y), fmaxf(s4.z, s4.w));
            #pragma unroll
            for (int off = 1; off < 8; off <<= 1)
                lm = fmaxf(lm, __shfl_xor(lm, off, 64));
            const float m_old = mrow[row];
            const float m_new = fmaxf(m_old, lm);
            float4 p;
            p.x = __expf(s4.x - m_new);
            p.y = __expf(s4.y - m_new);
            p.z = __expf(s4.z - m_new);
            p.w = __expf(s4.w - m_new);
            float ls = p.x + p.y + p.z + p.w;
            #pragma unroll
            for (int off = 1; off < 8; off <<= 1)
                ls += __shfl_xor(ls, off, 64);
            *(float4*)&Ss[row][j0] = p;
            if ((tid & 7) == 0) {
                const float alpha = __expf(m_old - m_new);  // 0 on first tile
                arow[row] = alpha;
                mrow[row] = m_new;
                lrow[row] = lrow[row]*alpha + ls;
            }
        }
        __syncthreads();

        // rescale O, then O += P @ V
        {
            const float a0 = arow[2*rq+0];
            const float a1 = arow[2*rq+1];
            #pragma unroll
            for (int j = 0; j < 8; ++j) { o[0][j] *= a0; o[1][j] *= a1; }
            #pragma unroll
            for (int s = 0; s < 32; ++s) {
                const float p0 = Ss[2*rq+0][s];
                const float p1 = Ss[2*rq+1][s];
                const float4 v0 = *(const float4*)&Vs[s][8*cq];
                const float4 v1 = *(const float4*)&Vs[s][8*cq+4];
                const float vv[8] = {v0.x, v0.y, v0.z, v0.w, v1.x, v1.y, v1.z, v1.w};
                #pragma unroll
                for (int j = 0; j < 8; ++j) {
                    o[0][j] = fmaf(p0, vv[j], o[0][j]);
                    o[1][j] = fmaf(p1, vv[j], o[1][j]);
                }
            }
        }
    }

    // normalize and store (lrow >= 1 always: max entry contributes exp(0)=1)
    {
        const float inv0 = 1.f / lrow[2*rq+0];
        const float inv1 = 1.f / lrow[2*rq+1];
        const size_t t0 = (size_t)(b*CTX) + qt*32 + 2*rq;
        float4 r0a = make_float4(o[0][0]*inv0, o[0][1]*inv0, o[0][2]*inv0, o[0][3]*inv0);
        float4 r0b = make_float4(o[0][4]*inv0, o[0][5]*inv0, o[0][6]*inv0, o[0][7]*inv0);
        float4 r1a = make_float4(o[1][0]*inv1, o[1][1]*inv1, o[1][2]*inv1, o[1][3]*inv1);
        float4 r1b = make_float4(o[1][4]*inv1, o[1][5]*inv1, o[1][6]*inv1, o[1][7]*inv1);
        *(float4*)&out[(t0+0)*HEAD + 8*cq]     = r0a;
        *(float4*)&out[(t0+0)*HEAD + 8*cq + 4] = r0b;
        *(float4*)&out[(t0+1)*HEAD + 8*cq]     = r1a;
        *(float4*)&out[(t0+1)*HEAD + 8*cq + 4] = r1b;
    }
}

// ---------------------------------------------------------------------------
extern "C" void kernel_launch(void* const* d_in, const int* in_sizes, int n_in,
                              void* d_out, int out_size, void* d_ws, size_t ws_size,
                              hipStream_t stream) {
    const float* x  = (const float*)d_in[0];
    const float* Wq = (const float*)d_in[1];
    const float* Wk = (const float*)d_in[2];
    const float* Wv = (const float*)d_in[3];
    float* out = (float*)d_out;

    const size_t nqkv = (size_t)BATCH * CTX * HEAD;   // 1,048,576 floats each
    float* q = (float*)d_ws;
    float* k = q + nqkv;
    float* v = k + nqkv;

    dim3 g1((BATCH * CTX) / 64, 3);
    qkv_proj_kernel<<<g1, 256, 0, stream>>>(x, Wq, Wk, Wv, q, k, v);

    dim3 g2(CTX / 32, BATCH);
    attn_kernel<<<g2, 256, 0, stream>>>(q, k, v, out);
}

// Round 2
// 272.902 us; speedup vs baseline: 3.0689x; 3.0689x over previous
//
#include <hip/hip_runtime.h>
#include <math.h>

#define BATCH 4
#define CTX   2048
#define EMB   1024
#define HEAD  128

typedef __attribute__((ext_vector_type(8))) short bf16x8;
typedef __attribute__((ext_vector_type(4))) float f32x4;

__device__ inline unsigned short f2bf(float f) {
    union { float f; unsigned u; } v; v.f = f;
    unsigned r = v.u + 0x7fffu + ((v.u >> 16) & 1u);
    return (unsigned short)(r >> 16);
}
__device__ inline unsigned pk2(float a, float b) {
    return (unsigned)f2bf(a) | ((unsigned)f2bf(b) << 16);
}

// ---------------------------------------------------------------------------
// W[1024][128] fp32 -> Wt[w][128][1024] bf16 (transposed), via LDS tiles.
// grid (16, 2, 3), 256 threads.
// ---------------------------------------------------------------------------
__global__ __launch_bounds__(256)
void transpose_w_kernel(const float* __restrict__ Wq, const float* __restrict__ Wk,
                        const float* __restrict__ Wv, unsigned short* __restrict__ Wt) {
    const int k0 = blockIdx.x * 64;
    const int h0 = blockIdx.y * 64;
    const int w  = blockIdx.z;
    const float* W = (w == 0) ? Wq : (w == 1) ? Wk : Wv;
    __shared__ float Ts[64][65];
    const int tid = threadIdx.x;
    #pragma unroll
    for (int it = 0; it < 4; ++it) {
        const int kk = (tid >> 4) + it * 16;
        const int c4 = (tid & 15) * 4;
        const float4 f = *(const float4*)&W[(size_t)(k0 + kk) * HEAD + h0 + c4];
        Ts[kk][c4 + 0] = f.x; Ts[kk][c4 + 1] = f.y;
        Ts[kk][c4 + 2] = f.z; Ts[kk][c4 + 3] = f.w;
    }
    __syncthreads();
    const int hr  = tid >> 2;
    const int kc0 = (tid & 3) * 16;
    union { unsigned short s[16]; uint4 q[2]; } tmp;
    #pragma unroll
    for (int i = 0; i < 16; ++i) tmp.s[i] = f2bf(Ts[kc0 + i][hr]);
    unsigned short* dst = &Wt[(size_t)w * HEAD * EMB + (size_t)(h0 + hr) * EMB + k0 + kc0];
    ((uint4*)dst)[0] = tmp.q[0];
    ((uint4*)dst)[1] = tmp.q[1];
}

// ---------------------------------------------------------------------------
// QKV projection via MFMA, no LDS. grid (128, 3), 256 threads (4 waves).
// Wave = 16 token rows. A/B frags are direct 16B global loads.
// q,k -> [t][h] bf16.  v -> vt[b][h][t] bf16 (operands swapped).
// ---------------------------------------------------------------------------
__global__ __launch_bounds__(256)
void proj_kernel(const float* __restrict__ x, const unsigned short* __restrict__ Wt,
                 unsigned short* __restrict__ qb, unsigned short* __restrict__ kb,
                 unsigned short* __restrict__ vt) {
    const int wsel = blockIdx.y;
    const int wv   = threadIdx.x >> 6;
    const int lane = threadIdx.x & 63;
    const int p = lane >> 4, c = lane & 15;
    const int m0 = (blockIdx.x * 4 + wv) * 16;
    const unsigned short* Wp = Wt + (size_t)wsel * HEAD * EMB;

    f32x4 acc[8];
    #pragma unroll
    for (int i = 0; i < 8; ++i) acc[i] = (f32x4){0.f, 0.f, 0.f, 0.f};

    if (wsel < 2) {
        for (int ks = 0; ks < EMB / 32; ++ks) {
            const float* xp = &x[(size_t)(m0 + c) * EMB + ks * 32 + p * 8];
            const float4 xa = *(const float4*)xp;
            const float4 xc = *(const float4*)(xp + 4);
            union { unsigned u[4]; bf16x8 v; } xf;
            xf.u[0] = pk2(xa.x, xa.y); xf.u[1] = pk2(xa.z, xa.w);
            xf.u[2] = pk2(xc.x, xc.y); xf.u[3] = pk2(xc.z, xc.w);
            #pragma unroll
            for (int nt = 0; nt < 8; ++nt) {
                const bf16x8 wf = *(const bf16x8*)&Wp[(size_t)(nt * 16 + c) * EMB + ks * 32 + p * 8];
                acc[nt] = __builtin_amdgcn_mfma_f32_16x16x32_bf16(xf.v, wf, acc[nt], 0, 0, 0);
            }
        }
        unsigned short* outp = (wsel == 0) ? qb : kb;
        #pragma unroll
        for (int nt = 0; nt < 8; ++nt)
            #pragma unroll
            for (int r = 0; r < 4; ++r)
                outp[(size_t)(m0 + p * 4 + r) * HEAD + nt * 16 + c] = f2bf(acc[nt][r]);
    } else {
        for (int ks = 0; ks < EMB / 32; ++ks) {
            const float* xp = &x[(size_t)(m0 + c) * EMB + ks * 32 + p * 8];
            const float4 xa = *(const float4*)xp;
            const float4 xc = *(const float4*)(xp + 4);
            union { unsigned u[4]; bf16x8 v; } xf;
            xf.u[0] = pk2(xa.x, xa.y); xf.u[1] = pk2(xa.z, xa.w);
            xf.u[2] = pk2(xc.x, xc.y); xf.u[3] = pk2(xc.z, xc.w);
            #pragma unroll
            for (int mt = 0; mt < 8; ++mt) {
                const bf16x8 wf = *(const bf16x8*)&Wp[(size_t)(mt * 16 + c) * EMB + ks * 32 + p * 8];
                acc[mt] = __builtin_amdgcn_mfma_f32_16x16x32_bf16(wf, xf.v, acc[mt], 0, 0, 0);
            }
        }
        // C[m = h = mt*16 + p*4 + r][n = token = m0 + c]
        const int token = m0 + c;
        const int b = token >> 11;
        const int t = token & (CTX - 1);
        #pragma unroll
        for (int mt = 0; mt < 8; ++mt)
            #pragma unroll
            for (int r = 0; r < 4; ++r)
                vt[((size_t)(b * HEAD) + mt * 16 + p * 4 + r) * CTX + t] = f2bf(acc[mt][r]);
    }
}

// ---------------------------------------------------------------------------
// Flash attention, MFMA, zero LDS. 512 single-wave blocks (64 thr).
// Wave owns 16 q rows; KV steps of 64. S^T = K*Q^T; O^T = V^T*P^T.
// P transpose C-layout -> B-layout via 8 packed shuffles per 32 kv.
// ---------------------------------------------------------------------------
__global__ __launch_bounds__(64)
void attn_kernel(const unsigned short* __restrict__ qb,
                 const unsigned short* __restrict__ kb,
                 const unsigned short* __restrict__ vt,
                 float* __restrict__ out) {
    const int bx   = blockIdx.x;
    const int b    = bx & 3;
    const int tile = 127 - (bx >> 2);     // longest-first dispatch
    const int lane = threadIdx.x;
    const int p = lane >> 4, c = lane & 15;
    const int t0 = tile * 16;
    const int qg = t0 + c;                // this lane's q row

    const unsigned short* qrow = qb + (size_t)(b * CTX) * HEAD;
    const unsigned short* krow = kb + (size_t)(b * CTX) * HEAD;
    const unsigned short* vrow = vt + (size_t)(b * HEAD) * CTX;

    bf16x8 qf[4];
    #pragma unroll
    for (int ks = 0; ks < 4; ++ks)
        qf[ks] = *(const bf16x8*)&qrow[(size_t)(t0 + c) * HEAD + ks * 32 + p * 8];

    f32x4 o[8];
    #pragma unroll
    for (int i = 0; i < 8; ++i) o[i] = (f32x4){0.f, 0.f, 0.f, 0.f};
    float m = -INFINITY, l = 0.f;

    const int  slA = 32 * (p & 1) + c;
    const int  slB = slA + 16;
    const bool thi = (p >> 1) != 0;
    const int  nsteps = (tile + 4) >> 2;
    const float scale = 0.08838834764831845f;   // 1/sqrt(128)

    for (int js = 0; js < nsteps; ++js) {
        const int c0 = js * 64;
        // S^T[kv = c0+nt*16+quad*4+r][q = t0 + lane&15]
        f32x4 st[4];
        #pragma unroll
        for (int nt = 0; nt < 4; ++nt) st[nt] = (f32x4){0.f, 0.f, 0.f, 0.f};
        #pragma unroll
        for (int nt = 0; nt < 4; ++nt) {
            const unsigned short* kp = &krow[(size_t)(c0 + nt * 16 + c) * HEAD];
            #pragma unroll
            for (int ks = 0; ks < 4; ++ks) {
                const bf16x8 kf = *(const bf16x8*)&kp[ks * 32 + p * 8];
                st[nt] = __builtin_amdgcn_mfma_f32_16x16x32_bf16(kf, qf[ks], st[nt], 0, 0, 0);
            }
        }
        // scale + causal mask + online softmax
        float s[4][4];
        float lm = -INFINITY;
        #pragma unroll
        for (int nt = 0; nt < 4; ++nt)
            #pragma unroll
            for (int r = 0; r < 4; ++r) {
                const int kv = c0 + nt * 16 + p * 4 + r;
                float v = st[nt][r] * scale;
                v = (kv <= qg) ? v : -INFINITY;
                s[nt][r] = v;
                lm = fmaxf(lm, v);
            }
        lm = fmaxf(lm, __shfl_xor(lm, 16, 64));
        lm = fmaxf(lm, __shfl_xor(lm, 32, 64));
        const float m_new = fmaxf(m, lm);
        const float alpha = __expf(m - m_new);
        float ls = 0.f;
        #pragma unroll
        for (int nt = 0; nt < 4; ++nt)
            #pragma unroll
            for (int r = 0; r < 4; ++r) {
                const float pv = __expf(s[nt][r] - m_new);
                s[nt][r] = pv;
                ls += pv;
            }
        ls += __shfl_xor(ls, 16, 64);
        ls += __shfl_xor(ls, 32, 64);
        l = l * alpha + ls;
        m = m_new;
        #pragma unroll
        for (int i = 0; i < 8; ++i) {
            o[i][0] *= alpha; o[i][1] *= alpha;
            o[i][2] *= alpha; o[i][3] *= alpha;
        }
        // P^T B-frags via shuffles, then O^T += V^T * P^T
        #pragma unroll
        for (int ch = 0; ch < 2; ++ch) {
            const unsigned pa0 = pk2(s[2*ch][0],     s[2*ch][1]);
            const unsigned pb0 = pk2(s[2*ch][2],     s[2*ch][3]);
            const unsigned pa1 = pk2(s[2*ch + 1][0], s[2*ch + 1][1]);
            const unsigned pb1 = pk2(s[2*ch + 1][2], s[2*ch + 1][3]);
            const unsigned u0a = __shfl((int)pa0, slA, 64), u0b = __shfl((int)pa1, slA, 64);
            const unsigned u1a = __shfl((int)pb0, slA, 64), u1b = __shfl((int)pb1, slA, 64);
            const unsigned u2a = __shfl((int)pa0, slB, 64), u2b = __shfl((int)pa1, slB, 64);
            const unsigned u3a = __shfl((int)pb0, slB, 64), u3b = __shfl((int)pb1, slB, 64);
            union { unsigned u[4]; bf16x8 v; } pf;
            pf.u[0] = thi ? u0b : u0a;
            pf.u[1] = thi ? u1b : u1a;
            pf.u[2] = thi ? u2b : u2a;
            pf.u[3] = thi ? u3b : u3a;
            const int kvo = c0 + ch * 32;
            #pragma unroll
            for (int mt = 0; mt < 8; ++mt) {
                const bf16x8 vf = *(const bf16x8*)&vrow[(size_t)(mt * 16 + c) * CTX + kvo + p * 8];
                o[mt] = __builtin_amdgcn_mfma_f32_16x16x32_bf16(vf, pf.v, o[mt], 0, 0, 0);
            }
        }
    }
    // O^T[h = mt*16+quad*4+r][q = t0+c] / l  ->  out[b, t0+c, h]
    const float linv = 1.f / l;
    float* orow = out + ((size_t)(b * CTX) + t0 + c) * HEAD;
    #pragma unroll
    for (int mt = 0; mt < 8; ++mt)
        #pragma unroll
        for (int r = 0; r < 4; ++r)
            orow[mt * 16 + p * 4 + r] = o[mt][r] * linv;
}

// ---------------------------------------------------------------------------
extern "C" void kernel_launch(void* const* d_in, const int* in_sizes, int n_in,
                              void* d_out, int out_size, void* d_ws, size_t ws_size,
                              hipStream_t stream) {
    const float* x  = (const float*)d_in[0];
    const float* Wq = (const float*)d_in[1];
    const float* Wk = (const float*)d_in[2];
    const float* Wv = (const float*)d_in[3];
    float* out = (float*)d_out;

    unsigned short* Wt = (unsigned short*)d_ws;                 // 3*128*1024
    unsigned short* qb = Wt + (size_t)3 * HEAD * EMB;           // 8192*128
    unsigned short* kb = qb + (size_t)BATCH * CTX * HEAD;
    unsigned short* vt = kb + (size_t)BATCH * CTX * HEAD;

    transpose_w_kernel<<<dim3(16, 2, 3), 256, 0, stream>>>(Wq, Wk, Wv, Wt);
    proj_kernel<<<dim3((BATCH * CTX) / 64, 3), 256, 0, stream>>>(x, Wt, qb, kb, vt);
    attn_kernel<<<BATCH * (CTX / 16), 64, 0, stream>>>(qb, kb, vt, out);
}

// Round 4
// 198.859 us; speedup vs baseline: 4.2115x; 1.3723x over previous
//
#include <hip/hip_runtime.h>

#define BATCH 4
#define CTX   2048
#define EMB   1024
#define HEAD  128

typedef __attribute__((ext_vector_type(8))) short bf16x8;
typedef __attribute__((ext_vector_type(4))) float f32x4;

#define FINF (__builtin_inff())
__device__ inline float fexp2(float x) { return __builtin_amdgcn_exp2f(x); }

__device__ inline unsigned short f2bf(float f) {
    union { float f; unsigned u; } v; v.f = f;
    unsigned r = v.u + 0x7fffu + ((v.u >> 16) & 1u);
    return (unsigned short)(r >> 16);
}
__device__ inline unsigned pk2(float a, float b) {
    return (unsigned)f2bf(a) | ((unsigned)f2bf(b) << 16);
}

// ---------------------------------------------------------------------------
// W[1024][128] fp32 -> Wt[w][128][1024] bf16 (transposed), via LDS tiles.
// grid (16, 2, 3), 256 threads.
// ---------------------------------------------------------------------------
__global__ __launch_bounds__(256)
void transpose_w_kernel(const float* __restrict__ Wq, const float* __restrict__ Wk,
                        const float* __restrict__ Wv, unsigned short* __restrict__ Wt) {
    const int k0 = blockIdx.x * 64;
    const int h0 = blockIdx.y * 64;
    const int w  = blockIdx.z;
    const float* W = (w == 0) ? Wq : (w == 1) ? Wk : Wv;
    __shared__ float Ts[64][65];
    const int tid = threadIdx.x;
    #pragma unroll
    for (int it = 0; it < 4; ++it) {
        const int kk = (tid >> 4) + it * 16;
        const int c4 = (tid & 15) * 4;
        const float4 f = *(const float4*)&W[(size_t)(k0 + kk) * HEAD + h0 + c4];
        Ts[kk][c4 + 0] = f.x; Ts[kk][c4 + 1] = f.y;
        Ts[kk][c4 + 2] = f.z; Ts[kk][c4 + 3] = f.w;
    }
    __syncthreads();
    const int hr  = tid >> 2;
    const int kc0 = (tid & 3) * 16;
    union { unsigned short s[16]; uint4 q[2]; } tmp;
    #pragma unroll
    for (int i = 0; i < 16; ++i) tmp.s[i] = f2bf(Ts[kc0 + i][hr]);
    unsigned short* dst = &Wt[(size_t)w * HEAD * EMB + (size_t)(h0 + hr) * EMB + k0 + kc0];
    ((uint4*)dst)[0] = tmp.q[0];
    ((uint4*)dst)[1] = tmp.q[1];
}

// ---------------------------------------------------------------------------
// QKV projection via MFMA, no LDS, register double-buffered loads.
// grid (128, 3), 256 threads (4 waves, wave = 16 token rows).
// Always computes C = W^T-frag * x-frag  ->  C[h][token].
// q,k -> [token][h] bf16 (packed uint2 stores).  v -> vt[b][h][t] bf16.
// ---------------------------------------------------------------------------
__global__ __launch_bounds__(256)
void proj_kernel(const float* __restrict__ x, const unsigned short* __restrict__ Wt,
                 unsigned short* __restrict__ qb, unsigned short* __restrict__ kb,
                 unsigned short* __restrict__ vt) {
    const int wsel = blockIdx.y;
    const int wv   = threadIdx.x >> 6;
    const int lane = threadIdx.x & 63;
    const int p = lane >> 4, c = lane & 15;
    const int m0 = (blockIdx.x * 4 + wv) * 16;

    const float* xbase = &x[(size_t)(m0 + c) * EMB + p * 8];
    const unsigned short* wbase = &Wt[(size_t)wsel * HEAD * EMB + (size_t)c * EMB + p * 8];

    f32x4 acc[8];
    #pragma unroll
    for (int i = 0; i < 8; ++i) acc[i] = (f32x4){0.f, 0.f, 0.f, 0.f};

    float4 xa0, xc0, xa1, xc1;
    bf16x8 w0[8], w1[8];

    auto ldx = [&](float4& xa, float4& xc, int ks) {
        const float* xp = xbase + ks * 32;
        xa = *(const float4*)xp;
        xc = *(const float4*)(xp + 4);
    };
    auto ldw = [&](bf16x8 (&wf)[8], int ks) {
        #pragma unroll
        for (int mt = 0; mt < 8; ++mt)
            wf[mt] = *(const bf16x8*)(wbase + (size_t)mt * 16 * EMB + ks * 32);
    };
    auto mm = [&](const float4& xa, const float4& xc, const bf16x8 (&wf)[8]) {
        union { unsigned u[4]; bf16x8 v; } xf;
        xf.u[0] = pk2(xa.x, xa.y); xf.u[1] = pk2(xa.z, xa.w);
        xf.u[2] = pk2(xc.x, xc.y); xf.u[3] = pk2(xc.z, xc.w);
        #pragma unroll
        for (int mt = 0; mt < 8; ++mt)
            acc[mt] = __builtin_amdgcn_mfma_f32_16x16x32_bf16(wf[mt], xf.v, acc[mt], 0, 0, 0);
    };

    ldx(xa0, xc0, 0); ldw(w0, 0);
    for (int ks = 0; ks < EMB / 32; ks += 2) {
        ldx(xa1, xc1, ks + 1); ldw(w1, ks + 1);        // prefetch odd
        mm(xa0, xc0, w0);
        if (ks + 2 < EMB / 32) { ldx(xa0, xc0, ks + 2); ldw(w0, ks + 2); }  // prefetch even
        mm(xa1, xc1, w1);
    }

    // C[h = mt*16 + p*4 + r][token = m0 + c]
    const int token = m0 + c;
    if (wsel < 2) {
        unsigned short* outp = (wsel == 0) ? qb : kb;
        #pragma unroll
        for (int mt = 0; mt < 8; ++mt) {
            union { unsigned short s[4]; uint2 u; } t;
            #pragma unroll
            for (int r = 0; r < 4; ++r) t.s[r] = f2bf(acc[mt][r]);
            *(uint2*)&outp[(size_t)token * HEAD + mt * 16 + p * 4] = t.u;
        }
    } else {
        const int b = token >> 11;
        const int t = token & (CTX - 1);
        #pragma unroll
        for (int mt = 0; mt < 8; ++mt)
            #pragma unroll
            for (int r = 0; r < 4; ++r)
                vt[((size_t)(b * HEAD) + mt * 16 + p * 4 + r) * CTX + t] = f2bf(acc[mt][r]);
    }
}

// ---------------------------------------------------------------------------
// Flash attention, MFMA, zero LDS, register-pipelined.
// 512 single-wave blocks. Wave = 16 q rows; KV steps of 64.
// K double-buffered one step ahead; V batch-loaded at step top (consumed
// after softmax). Causal mask only on the last step (diagonal provably
// only intersects js == nsteps-1). Softmax in base-2 (v_exp_f32 native).
// ---------------------------------------------------------------------------
__global__ __launch_bounds__(64)
void attn_kernel(const unsigned short* __restrict__ qb,
                 const unsigned short* __restrict__ kb,
                 const unsigned short* __restrict__ vt,
                 float* __restrict__ out) {
    const int bx   = blockIdx.x;
    const int b    = bx & 3;
    const int tile = 127 - (bx >> 2);     // longest-first dispatch
    const int lane = threadIdx.x;
    const int p = lane >> 4, c = lane & 15;
    const int t0 = tile * 16;
    const int qg = t0 + c;

    const unsigned short* kbase = kb + ((size_t)(b * CTX) + c) * HEAD + p * 8;
    const unsigned short* vbase = vt + ((size_t)(b * HEAD) + c) * CTX + p * 8;

    bf16x8 qf[4];
    #pragma unroll
    for (int ks = 0; ks < 4; ++ks)
        qf[ks] = *(const bf16x8*)&qb[((size_t)(b * CTX) + t0 + c) * HEAD + ks * 32 + p * 8];

    f32x4 o[8];
    #pragma unroll
    for (int i = 0; i < 8; ++i) o[i] = (f32x4){0.f, 0.f, 0.f, 0.f};
    float m = -FINF, l = 0.f;

    const int  slA = 32 * (p & 1) + c;
    const int  slB = slA + 16;
    const bool thi = (p >> 1) != 0;
    const int  nsteps = (tile + 4) >> 2;
    const float scale2 = 0.08838834764831845f * 1.44269504088896340f;  // 1/sqrt(128)*log2(e)

    bf16x8 kA[4][4], kB[4][4], vfr[2][8];

    auto load_k = [&](bf16x8 (&kf)[4][4], int js) {
        const size_t off = (size_t)(js * 64) * HEAD;
        #pragma unroll
        for (int nt = 0; nt < 4; ++nt)
            #pragma unroll
            for (int ks = 0; ks < 4; ++ks)
                kf[nt][ks] = *(const bf16x8*)&kbase[off + (size_t)nt * 16 * HEAD + ks * 32];
    };
    auto load_v = [&](int js) {
        #pragma unroll
        for (int ch = 0; ch < 2; ++ch)
            #pragma unroll
            for (int mt = 0; mt < 8; ++mt)
                vfr[ch][mt] = *(const bf16x8*)&vbase[(size_t)mt * 16 * CTX + js * 64 + ch * 32];
    };
    auto step = [&](const bf16x8 (&kf)[4][4], int js, bool domask) {
        const int c0 = js * 64;
        f32x4 st[4];
        #pragma unroll
        for (int nt = 0; nt < 4; ++nt) st[nt] = (f32x4){0.f, 0.f, 0.f, 0.f};
        #pragma unroll
        for (int ks = 0; ks < 4; ++ks)
            #pragma unroll
            for (int nt = 0; nt < 4; ++nt)
                st[nt] = __builtin_amdgcn_mfma_f32_16x16x32_bf16(kf[nt][ks], qf[ks], st[nt], 0, 0, 0);

        float s[4][4];
        float lm = -FINF;
        if (domask) {
            #pragma unroll
            for (int nt = 0; nt < 4; ++nt)
                #pragma unroll
                for (int r = 0; r < 4; ++r) {
                    const int kv = c0 + nt * 16 + p * 4 + r;
                    float v = st[nt][r] * scale2;
                    v = (kv <= qg) ? v : -FINF;
                    s[nt][r] = v;
                    lm = fmaxf(lm, v);
                }
        } else {
            #pragma unroll
            for (int nt = 0; nt < 4; ++nt)
                #pragma unroll
                for (int r = 0; r < 4; ++r) {
                    const float v = st[nt][r] * scale2;
                    s[nt][r] = v;
                    lm = fmaxf(lm, v);
                }
        }
        lm = fmaxf(lm, __shfl_xor(lm, 16, 64));
        lm = fmaxf(lm, __shfl_xor(lm, 32, 64));
        const float m_new = fmaxf(m, lm);
        const float alpha = fexp2(m - m_new);
        float ls = 0.f;
        #pragma unroll
        for (int nt = 0; nt < 4; ++nt)
            #pragma unroll
            for (int r = 0; r < 4; ++r) {
                const float pv = fexp2(s[nt][r] - m_new);
                s[nt][r] = pv;
                ls += pv;
            }
        ls += __shfl_xor(ls, 16, 64);
        ls += __shfl_xor(ls, 32, 64);
        l = l * alpha + ls;
        m = m_new;
        #pragma unroll
        for (int i = 0; i < 8; ++i) {
            o[i][0] *= alpha; o[i][1] *= alpha;
            o[i][2] *= alpha; o[i][3] *= alpha;
        }
        #pragma unroll
        for (int ch = 0; ch < 2; ++ch) {
            const unsigned pa0 = pk2(s[2*ch][0],     s[2*ch][1]);
            const unsigned pb0 = pk2(s[2*ch][2],     s[2*ch][3]);
            const unsigned pa1 = pk2(s[2*ch + 1][0], s[2*ch + 1][1]);
            const unsigned pb1 = pk2(s[2*ch + 1][2], s[2*ch + 1][3]);
            const unsigned u0a = __shfl((int)pa0, slA, 64), u0b = __shfl((int)pa1, slA, 64);
            const unsigned u1a = __shfl((int)pb0, slA, 64), u1b = __shfl((int)pb1, slA, 64);
            const unsigned u2a = __shfl((int)pa0, slB, 64), u2b = __shfl((int)pa1, slB, 64);
            const unsigned u3a = __shfl((int)pb0, slB, 64), u3b = __shfl((int)pb1, slB, 64);
            union { unsigned u[4]; bf16x8 v; } pf;
            pf.u[0] = thi ? u0b : u0a;
            pf.u[1] = thi ? u1b : u1a;
            pf.u[2] = thi ? u2b : u2a;
            pf.u[3] = thi ? u3b : u3a;
            #pragma unroll
            for (int mt = 0; mt < 8; ++mt)
                o[mt] = __builtin_amdgcn_mfma_f32_16x16x32_bf16(vfr[ch][mt], pf.v, o[mt], 0, 0, 0);
        }
    };

    load_k(kA, 0);
    int js = 0;
    while (true) {
        load_v(js);
        if (js + 1 < nsteps) load_k(kB, js + 1);
        step(kA, js, js == nsteps - 1);
        if (++js >= nsteps) break;
        load_v(js);
        if (js + 1 < nsteps) load_k(kA, js + 1);
        step(kB, js, js == nsteps - 1);
        if (++js >= nsteps) break;
    }

    // O^T[h = mt*16 + p*4 + r][q = t0 + c] / l  ->  out[b, t0+c, h], float4 stores
    const float linv = 1.f / l;
    float* orow = out + ((size_t)(b * CTX) + t0 + c) * HEAD;
    #pragma unroll
    for (int mt = 0; mt < 8; ++mt) {
        float4 ov = make_float4(o[mt][0] * linv, o[mt][1] * linv,
                                o[mt][2] * linv, o[mt][3] * linv);
        *(float4*)&orow[mt * 16 + p * 4] = ov;
    }
}

// ---------------------------------------------------------------------------
extern "C" void kernel_launch(void* const* d_in, const int* in_sizes, int n_in,
                              void* d_out, int out_size, void* d_ws, size_t ws_size,
                              hipStream_t stream) {
    const float* x  = (const float*)d_in[0];
    const float* Wq = (const float*)d_in[1];
    const float* Wk = (const float*)d_in[2];
    const float* Wv = (const float*)d_in[3];
    float* out = (float*)d_out;

    unsigned short* Wt = (unsigned short*)d_ws;                 // 3*128*1024
    unsigned short* qb = Wt + (size_t)3 * HEAD * EMB;           // 8192*128
    unsigned short* kb = qb + (size_t)BATCH * CTX * HEAD;
    unsigned short* vt = kb + (size_t)BATCH * CTX * HEAD;

    transpose_w_kernel<<<dim3(16, 2, 3), 256, 0, stream>>>(Wq, Wk, Wv, Wt);
    proj_kernel<<<dim3((BATCH * CTX) / 64, 3), 256, 0, stream>>>(x, Wt, qb, kb, vt);
    attn_kernel<<<BATCH * (CTX / 16), 64, 0, stream>>>(qb, kb, vt, out);
}

// Round 5
// 181.281 us; speedup vs baseline: 4.6199x; 1.0970x over previous
//
#include <hip/hip_runtime.h>

#define BATCH 4
#define CTX   2048
#define EMB   1024
#define HEAD  128

typedef __attribute__((ext_vector_type(8))) short bf16x8;
typedef __attribute__((ext_vector_type(4))) float f32x4;

#define FINF (__builtin_inff())
__device__ inline float fexp2(float x) { return __builtin_amdgcn_exp2f(x); }

__device__ inline unsigned short f2bf(float f) {
    union { float f; unsigned u; } v; v.f = f;
    unsigned r = v.u + 0x7fffu + ((v.u >> 16) & 1u);
    return (unsigned short)(r >> 16);
}
__device__ inline unsigned pk2(float a, float b) {
    return (unsigned)f2bf(a) | ((unsigned)f2bf(b) << 16);
}

// ---------------------------------------------------------------------------
// W[1024][128] fp32 -> Wt[w][128][1024] bf16 (transposed), via LDS tiles.
// grid (16, 2, 3), 256 threads.
// ---------------------------------------------------------------------------
__global__ __launch_bounds__(256)
void transpose_w_kernel(const float* __restrict__ Wq, const float* __restrict__ Wk,
                        const float* __restrict__ Wv, unsigned short* __restrict__ Wt) {
    const int k0 = blockIdx.x * 64;
    const int h0 = blockIdx.y * 64;
    const int w  = blockIdx.z;
    const float* W = (w == 0) ? Wq : (w == 1) ? Wk : Wv;
    __shared__ float Ts[64][65];
    const int tid = threadIdx.x;
    #pragma unroll
    for (int it = 0; it < 4; ++it) {
        const int kk = (tid >> 4) + it * 16;
        const int c4 = (tid & 15) * 4;
        const float4 f = *(const float4*)&W[(size_t)(k0 + kk) * HEAD + h0 + c4];
        Ts[kk][c4 + 0] = f.x; Ts[kk][c4 + 1] = f.y;
        Ts[kk][c4 + 2] = f.z; Ts[kk][c4 + 3] = f.w;
    }
    __syncthreads();
    const int hr  = tid >> 2;
    const int kc0 = (tid & 3) * 16;
    union { unsigned short s[16]; uint4 q[2]; } tmp;
    #pragma unroll
    for (int i = 0; i < 16; ++i) tmp.s[i] = f2bf(Ts[kc0 + i][hr]);
    unsigned short* dst = &Wt[(size_t)w * HEAD * EMB + (size_t)(h0 + hr) * EMB + k0 + kc0];
    ((uint4*)dst)[0] = tmp.q[0];
    ((uint4*)dst)[1] = tmp.q[1];
}

// ---------------------------------------------------------------------------
// QKV projection via MFMA, no LDS, 4-deep register-pipelined loads.
// grid (256, 3), 128 threads (2 waves, wave = 16 token rows).
// launch_bounds(128,2): VGPR cap 256 so the prefetch buffers (~210 VGPR)
// actually live in registers (R4: default bounds forced 64 VGPR -> compiler
// sank all prefetches -> serial 600-cyc load chains, 77 us).
// C = W^T-frag * x-frag -> C[h][token].
// q,k -> [token][h] bf16.  v -> vt[b][h][t] bf16.
// ---------------------------------------------------------------------------
__global__ __launch_bounds__(128, 2)
void proj_kernel(const float* __restrict__ x, const unsigned short* __restrict__ Wt,
                 unsigned short* __restrict__ qb, unsigned short* __restrict__ kb,
                 unsigned short* __restrict__ vt) {
    const int wsel = blockIdx.y;
    const int wv   = threadIdx.x >> 6;
    const int lane = threadIdx.x & 63;
    const int p = lane >> 4, c = lane & 15;
    const int m0 = (blockIdx.x * 2 + wv) * 16;

    const float* xbase = &x[(size_t)(m0 + c) * EMB + p * 8];
    const unsigned short* wbase = &Wt[(size_t)wsel * HEAD * EMB + (size_t)c * EMB + p * 8];

    f32x4 acc[8];
    #pragma unroll
    for (int i = 0; i < 8; ++i) acc[i] = (f32x4){0.f, 0.f, 0.f, 0.f};

    float4 xa[4], xc[4];
    bf16x8 wb[4][8];

    auto ldx = [&](float4& a, float4& cc, int ks) {
        const float* xp = xbase + ks * 32;
        a  = *(const float4*)xp;
        cc = *(const float4*)(xp + 4);
    };
    auto ldw = [&](bf16x8 (&wf)[8], int ks) {
        #pragma unroll
        for (int mt = 0; mt < 8; ++mt)
            wf[mt] = *(const bf16x8*)(wbase + (size_t)mt * 16 * EMB + ks * 32);
    };
    auto mm = [&](const float4& a, const float4& cc, const bf16x8 (&wf)[8]) {
        union { unsigned u[4]; bf16x8 v; } xf;
        xf.u[0] = pk2(a.x, a.y);   xf.u[1] = pk2(a.z, a.w);
        xf.u[2] = pk2(cc.x, cc.y); xf.u[3] = pk2(cc.z, cc.w);
        #pragma unroll
        for (int mt = 0; mt < 8; ++mt)
            acc[mt] = __builtin_amdgcn_mfma_f32_16x16x32_bf16(wf[mt], xf.v, acc[mt], 0, 0, 0);
    };

    // 4-deep software pipeline over EMB/32 = 32 K-steps
    #pragma unroll
    for (int i = 0; i < 4; ++i) { ldx(xa[i], xc[i], i); ldw(wb[i], i); }
    for (int ks = 0; ks < 28; ks += 4) {
        #pragma unroll
        for (int u = 0; u < 4; ++u) {
            mm(xa[u], xc[u], wb[u]);
            ldx(xa[u], xc[u], ks + u + 4);
            ldw(wb[u], ks + u + 4);
        }
    }
    #pragma unroll
    for (int u = 0; u < 4; ++u) mm(xa[u], xc[u], wb[u]);

    // C[h = mt*16 + p*4 + r][token = m0 + c]
    const int token = m0 + c;
    if (wsel < 2) {
        unsigned short* outp = (wsel == 0) ? qb : kb;
        #pragma unroll
        for (int mt = 0; mt < 8; ++mt) {
            union { unsigned short s[4]; uint2 u; } t;
            #pragma unroll
            for (int r = 0; r < 4; ++r) t.s[r] = f2bf(acc[mt][r]);
            *(uint2*)&outp[(size_t)token * HEAD + mt * 16 + p * 4] = t.u;
        }
    } else {
        const int b = token >> 11;
        const int t = token & (CTX - 1);
        #pragma unroll
        for (int mt = 0; mt < 8; ++mt)
            #pragma unroll
            for (int r = 0; r < 4; ++r)
                vt[((size_t)(b * HEAD) + mt * 16 + p * 4 + r) * CTX + t] = f2bf(acc[mt][r]);
    }
}

// ---------------------------------------------------------------------------
// Flash attention, MFMA, zero LDS, register-pipelined.
// 512 single-wave blocks (all co-resident at 2 blocks/CU). Wave = 16 q rows;
// KV steps of 64. K double-buffered one step ahead; V batch-loaded at step
// top. launch_bounds(64,1): VGPR cap 512 so kA/kB/vfr (~290 VGPR) stay in
// registers instead of being re-sunk into serial load chains (R4 disease).
// ---------------------------------------------------------------------------
__global__ __launch_bounds__(64, 1)
void attn_kernel(const unsigned short* __restrict__ qb,
                 const unsigned short* __restrict__ kb,
                 const unsigned short* __restrict__ vt,
                 float* __restrict__ out) {
    const int bx   = blockIdx.x;
    const int b    = bx & 3;
    const int tile = 127 - (bx >> 2);     // longest-first dispatch
    const int lane = threadIdx.x;
    const int p = lane >> 4, c = lane & 15;
    const int t0 = tile * 16;
    const int qg = t0 + c;

    const unsigned short* kbase = kb + ((size_t)(b * CTX) + c) * HEAD + p * 8;
    const unsigned short* vbase = vt + ((size_t)(b * HEAD) + c) * CTX + p * 8;

    bf16x8 qf[4];
    #pragma unroll
    for (int ks = 0; ks < 4; ++ks)
        qf[ks] = *(const bf16x8*)&qb[((size_t)(b * CTX) + t0 + c) * HEAD + ks * 32 + p * 8];

    f32x4 o[8];
    #pragma unroll
    for (int i = 0; i < 8; ++i) o[i] = (f32x4){0.f, 0.f, 0.f, 0.f};
    float m = -FINF, l = 0.f;

    const int  slA = 32 * (p & 1) + c;
    const int  slB = slA + 16;
    const bool thi = (p >> 1) != 0;
    const int  nsteps = (tile + 4) >> 2;
    const float scale2 = 0.08838834764831845f * 1.44269504088896340f;  // 1/sqrt(128)*log2(e)

    bf16x8 kA[4][4], kB[4][4], vfr[2][8];

    auto load_k = [&](bf16x8 (&kf)[4][4], int js) {
        const size_t off = (size_t)(js * 64) * HEAD;
        #pragma unroll
        for (int nt = 0; nt < 4; ++nt)
            #pragma unroll
            for (int ks = 0; ks < 4; ++ks)
                kf[nt][ks] = *(const bf16x8*)&kbase[off + (size_t)nt * 16 * HEAD + ks * 32];
    };
    auto load_v = [&](int js) {
        #pragma unroll
        for (int ch = 0; ch < 2; ++ch)
            #pragma unroll
            for (int mt = 0; mt < 8; ++mt)
                vfr[ch][mt] = *(const bf16x8*)&vbase[(size_t)mt * 16 * CTX + js * 64 + ch * 32];
    };
    auto step = [&](const bf16x8 (&kf)[4][4], int js, bool domask) {
        const int c0 = js * 64;
        f32x4 st[4];
        #pragma unroll
        for (int nt = 0; nt < 4; ++nt) st[nt] = (f32x4){0.f, 0.f, 0.f, 0.f};
        #pragma unroll
        for (int ks = 0; ks < 4; ++ks)
            #pragma unroll
            for (int nt = 0; nt < 4; ++nt)
                st[nt] = __builtin_amdgcn_mfma_f32_16x16x32_bf16(kf[nt][ks], qf[ks], st[nt], 0, 0, 0);

        float s[4][4];
        float lm = -FINF;
        if (domask) {
            #pragma unroll
            for (int nt = 0; nt < 4; ++nt)
                #pragma unroll
                for (int r = 0; r < 4; ++r) {
                    const int kv = c0 + nt * 16 + p * 4 + r;
                    float v = st[nt][r] * scale2;
                    v = (kv <= qg) ? v : -FINF;
                    s[nt][r] = v;
                    lm = fmaxf(lm, v);
                }
        } else {
            #pragma unroll
            for (int nt = 0; nt < 4; ++nt)
                #pragma unroll
                for (int r = 0; r < 4; ++r) {
                    const float v = st[nt][r] * scale2;
                    s[nt][r] = v;
                    lm = fmaxf(lm, v);
                }
        }
        lm = fmaxf(lm, __shfl_xor(lm, 16, 64));
        lm = fmaxf(lm, __shfl_xor(lm, 32, 64));
        const float m_new = fmaxf(m, lm);
        const float alpha = fexp2(m - m_new);
        float ls = 0.f;
        #pragma unroll
        for (int nt = 0; nt < 4; ++nt)
            #pragma unroll
            for (int r = 0; r < 4; ++r) {
                const float pv = fexp2(s[nt][r] - m_new);
                s[nt][r] = pv;
                ls += pv;
            }
        ls += __shfl_xor(ls, 16, 64);
        ls += __shfl_xor(ls, 32, 64);
        l = l * alpha + ls;
        m = m_new;
        #pragma unroll
        for (int i = 0; i < 8; ++i) {
            o[i][0] *= alpha; o[i][1] *= alpha;
            o[i][2] *= alpha; o[i][3] *= alpha;
        }
        #pragma unroll
        for (int ch = 0; ch < 2; ++ch) {
            const unsigned pa0 = pk2(s[2*ch][0],     s[2*ch][1]);
            const unsigned pb0 = pk2(s[2*ch][2],     s[2*ch][3]);
            const unsigned pa1 = pk2(s[2*ch + 1][0], s[2*ch + 1][1]);
            const unsigned pb1 = pk2(s[2*ch + 1][2], s[2*ch + 1][3]);
            const unsigned u0a = __shfl((int)pa0, slA, 64), u0b = __shfl((int)pa1, slA, 64);
            const unsigned u1a = __shfl((int)pb0, slA, 64), u1b = __shfl((int)pb1, slA, 64);
            const unsigned u2a = __shfl((int)pa0, slB, 64), u2b = __shfl((int)pa1, slB, 64);
            const unsigned u3a = __shfl((int)pb0, slB, 64), u3b = __shfl((int)pb1, slB, 64);
            union { unsigned u[4]; bf16x8 v; } pf;
            pf.u[0] = thi ? u0b : u0a;
            pf.u[1] = thi ? u1b : u1a;
            pf.u[2] = thi ? u2b : u2a;
            pf.u[3] = thi ? u3b : u3a;
            #pragma unroll
            for (int mt = 0; mt < 8; ++mt)
                o[mt] = __builtin_amdgcn_mfma_f32_16x16x32_bf16(vfr[ch][mt], pf.v, o[mt], 0, 0, 0);
        }
    };

    load_k(kA, 0);
    int js = 0;
    while (true) {
        load_v(js);
        if (js + 1 < nsteps) load_k(kB, js + 1);
        step(kA, js, js == nsteps - 1);
        if (++js >= nsteps) break;
        load_v(js);
        if (js + 1 < nsteps) load_k(kA, js + 1);
        step(kB, js, js == nsteps - 1);
        if (++js >= nsteps) break;
    }

    // O^T[h = mt*16 + p*4 + r][q = t0 + c] / l  ->  out[b, t0+c, h]
    const float linv = 1.f / l;
    float* orow = out + ((size_t)(b * CTX) + t0 + c) * HEAD;
    #pragma unroll
    for (int mt = 0; mt < 8; ++mt) {
        float4 ov = make_float4(o[mt][0] * linv, o[mt][1] * linv,
                                o[mt][2] * linv, o[mt][3] * linv);
        *(float4*)&orow[mt * 16 + p * 4] = ov;
    }
}

// ---------------------------------------------------------------------------
extern "C" void kernel_launch(void* const* d_in, const int* in_sizes, int n_in,
                              void* d_out, int out_size, void* d_ws, size_t ws_size,
                              hipStream_t stream) {
    const float* x  = (const float*)d_in[0];
    const float* Wq = (const float*)d_in[1];
    const float* Wk = (const float*)d_in[2];
    const float* Wv = (const float*)d_in[3];
    float* out = (float*)d_out;

    unsigned short* Wt = (unsigned short*)d_ws;                 // 3*128*1024
    unsigned short* qb = Wt + (size_t)3 * HEAD * EMB;           // 8192*128
    unsigned short* kb = qb + (size_t)BATCH * CTX * HEAD;
    unsigned short* vt = kb + (size_t)BATCH * CTX * HEAD;

    transpose_w_kernel<<<dim3(16, 2, 3), 256, 0, stream>>>(Wq, Wk, Wv, Wt);
    proj_kernel<<<dim3((BATCH * CTX) / 32, 3), 128, 0, stream>>>(x, Wt, qb, kb, vt);
    attn_kernel<<<BATCH * (CTX / 16), 64, 0, stream>>>(qb, kb, vt, out);
}

// Round 6
// 145.991 us; speedup vs baseline: 5.7366x; 1.2417x over previous
//
#include <hip/hip_runtime.h>

#define BATCH 4
#define CTX   2048
#define EMB   1024
#define HEAD  128

typedef __attribute__((ext_vector_type(8))) short bf16x8;
typedef __attribute__((ext_vector_type(4))) float f32x4;
typedef const __attribute__((address_space(1))) unsigned int* gas_t;
typedef __attribute__((address_space(3))) unsigned int* las_t;

#define FINF (__builtin_inff())
__device__ inline float fexp2(float x) { return __builtin_amdgcn_exp2f(x); }

// async global->LDS, 16B per lane. LDS dest = wave-uniform base + lane*16
// (m104/m108). No VGPR destination => register allocator cannot sink it.
__device__ inline void cp16(const void* g, void* l) {
    __builtin_amdgcn_global_load_lds((gas_t)g, (las_t)l, 16, 0, 0);
}

__device__ inline unsigned short f2bf(float f) {
    union { float f; unsigned u; } v; v.f = f;
    unsigned r = v.u + 0x7fffu + ((v.u >> 16) & 1u);
    return (unsigned short)(r >> 16);
}
__device__ inline unsigned pk2(float a, float b) {
    return (unsigned)f2bf(a) | ((unsigned)f2bf(b) << 16);
}

// ---------------------------------------------------------------------------
// W[1024][128] fp32 -> Wt[w][128][1024] bf16 (transposed). grid (16,2,3).
// ---------------------------------------------------------------------------
__global__ __launch_bounds__(256)
void transpose_w_kernel(const float* __restrict__ Wq, const float* __restrict__ Wk,
                        const float* __restrict__ Wv, unsigned short* __restrict__ Wt) {
    const int k0 = blockIdx.x * 64;
    const int h0 = blockIdx.y * 64;
    const int w  = blockIdx.z;
    const float* W = (w == 0) ? Wq : (w == 1) ? Wk : Wv;
    __shared__ float Ts[64][65];
    const int tid = threadIdx.x;
    #pragma unroll
    for (int it = 0; it < 4; ++it) {
        const int kk = (tid >> 4) + it * 16;
        const int c4 = (tid & 15) * 4;
        const float4 f = *(const float4*)&W[(size_t)(k0 + kk) * HEAD + h0 + c4];
        Ts[kk][c4 + 0] = f.x; Ts[kk][c4 + 1] = f.y;
        Ts[kk][c4 + 2] = f.z; Ts[kk][c4 + 3] = f.w;
    }
    __syncthreads();
    const int hr  = tid >> 2;
    const int kc0 = (tid & 3) * 16;
    union { unsigned short s[16]; uint4 q[2]; } tmp;
    #pragma unroll
    for (int i = 0; i < 16; ++i) tmp.s[i] = f2bf(Ts[kc0 + i][hr]);
    unsigned short* dst = &Wt[(size_t)w * HEAD * EMB + (size_t)(h0 + hr) * EMB + k0 + kc0];
    ((uint4*)dst)[0] = tmp.q[0];
    ((uint4*)dst)[1] = tmp.q[1];
}

// ---------------------------------------------------------------------------
// QKV projection: m97-style LDS double-buffered MFMA GEMM.
// BM=32 tokens, BN=128(=H), BK=32, 128 threads (2 waves), grid (256,3)=768
// blocks = 3/CU. A = x (fp32, converted at frag read), B = Wt (bf16), staged
// via global_load_lds with XOR slot swizzle (<=2-way LDS conflicts = free).
// wsel<2: C[token][h] -> qb/kb. wsel==2: operands swapped -> vt[h][t].
// ---------------------------------------------------------------------------
__global__ __launch_bounds__(128, 3)
void proj_kernel(const float* __restrict__ x, const unsigned short* __restrict__ Wt,
                 unsigned short* __restrict__ qb, unsigned short* __restrict__ kb,
                 unsigned short* __restrict__ vt) {
    __shared__ __align__(16) char smem[24576];
    char* Ab = smem;            // 2 x 4KB : x tile [32 tok][32 k] fp32
    char* Bb = smem + 8192;     // 2 x 8KB : W tile [128 h][32 k] bf16

    const int wsel = blockIdx.y;
    const int tid  = threadIdx.x;
    const int wv   = tid >> 6;
    const int lane = tid & 63;
    const int p = lane >> 4, c = lane & 15;
    const int m0 = blockIdx.x * 32;
    const unsigned short* Wp = Wt + (size_t)wsel * HEAD * EMB;

    const int u7  = c & 7;                 // A-row swizzle key (row&7 == c&7)
    const int u2c = (c ^ (c >> 2)) & 3;    // B-row swizzle key ((h^(h>>2))&3)

    auto stage = [&](int bi, int ks) {
        #pragma unroll
        for (int i = 0; i < 2; ++i) {      // A: 32 rows x 128B
            const int f = i * 128 + tid;
            const int r = f >> 3, s = f & 7, q = s ^ (r & 7);
            cp16(&x[(size_t)(m0 + r) * EMB + ks * 32 + q * 4],
                 Ab + bi * 4096 + i * 2048 + wv * 1024);
        }
        #pragma unroll
        for (int i = 0; i < 4; ++i) {      // B: 128 rows x 64B
            const int f = i * 128 + tid;
            const int h = f >> 2, s = f & 3, q = s ^ ((h ^ (h >> 2)) & 3);
            cp16(&Wp[(size_t)h * EMB + ks * 32 + q * 8],
                 Bb + bi * 8192 + i * 2048 + wv * 1024);
        }
    };

    // x-fragment builder: LDS fp32 row r -> packed bf16x8 (k = p*8..p*8+8)
    auto xfrag = [&](const char* Ac, int r) {
        const float4 a0 = *(const float4*)(Ac + r * 128 + (((2 * p)     ^ u7) * 16));
        const float4 a1 = *(const float4*)(Ac + r * 128 + (((2 * p + 1) ^ u7) * 16));
        union { unsigned u[4]; bf16x8 v; } xf;
        xf.u[0] = pk2(a0.x, a0.y); xf.u[1] = pk2(a0.z, a0.w);
        xf.u[2] = pk2(a1.x, a1.y); xf.u[3] = pk2(a1.z, a1.w);
        return xf.v;
    };

    if (wsel < 2) {
        f32x4 acc[8];
        #pragma unroll
        for (int i = 0; i < 8; ++i) acc[i] = (f32x4){0.f, 0.f, 0.f, 0.f};
        stage(0, 0);
        for (int ks = 0; ks < 32; ++ks) {
            const int cur = ks & 1;
            __syncthreads();                       // drains vmcnt -> buf[cur] ready
            if (ks + 1 < 32) stage(cur ^ 1, ks + 1);
            const bf16x8 xv = xfrag(Ab + cur * 4096, wv * 16 + c);
            const char* Bc = Bb + cur * 8192;
            #pragma unroll
            for (int nt = 0; nt < 8; ++nt) {
                const int h = nt * 16 + c;
                const bf16x8 wf = *(const bf16x8*)(Bc + h * 64 + ((p ^ u2c) * 16));
                acc[nt] = __builtin_amdgcn_mfma_f32_16x16x32_bf16(xv, wf, acc[nt], 0, 0, 0);
            }
        }
        // C[m = token = m0+wv*16+p*4+rr][n = h = nt*16+c]
        unsigned short* outp = (wsel == 0) ? qb : kb;
        #pragma unroll
        for (int rr = 0; rr < 4; ++rr) {
            unsigned short* orow = outp + (size_t)(m0 + wv * 16 + p * 4 + rr) * HEAD + c;
            #pragma unroll
            for (int nt = 0; nt < 8; ++nt)
                orow[nt * 16] = f2bf(acc[nt][rr]);
        }
    } else {
        f32x4 acc[4][2];
        #pragma unroll
        for (int i = 0; i < 4; ++i)
            #pragma unroll
            for (int j = 0; j < 2; ++j) acc[i][j] = (f32x4){0.f, 0.f, 0.f, 0.f};
        stage(0, 0);
        for (int ks = 0; ks < 32; ++ks) {
            const int cur = ks & 1;
            __syncthreads();
            if (ks + 1 < 32) stage(cur ^ 1, ks + 1);
            const char* Ac = Ab + cur * 4096;
            const char* Bc = Bb + cur * 8192;
            bf16x8 xv[2];
            #pragma unroll
            for (int n2 = 0; n2 < 2; ++n2) xv[n2] = xfrag(Ac, n2 * 16 + c);
            #pragma unroll
            for (int mt = 0; mt < 4; ++mt) {
                const int h = wv * 64 + mt * 16 + c;
                const bf16x8 wf = *(const bf16x8*)(Bc + h * 64 + ((p ^ u2c) * 16));
                #pragma unroll
                for (int n2 = 0; n2 < 2; ++n2)
                    acc[mt][n2] = __builtin_amdgcn_mfma_f32_16x16x32_bf16(wf, xv[n2], acc[mt][n2], 0, 0, 0);
            }
        }
        // C[m = h = wv*64+mt*16+p*4+rr][n = token = m0+n2*16+c] -> vt[b][h][t]
        const int bidx = m0 >> 11;
        const int tl   = m0 & (CTX - 1);
        unsigned short* vbp = vt + (size_t)bidx * HEAD * CTX;
        #pragma unroll
        for (int mt = 0; mt < 4; ++mt)
            #pragma unroll
            for (int rr = 0; rr < 4; ++rr) {
                const int h = wv * 64 + mt * 16 + p * 4 + rr;
                #pragma unroll
                for (int n2 = 0; n2 < 2; ++n2)
                    vbp[(size_t)h * CTX + tl + n2 * 16 + c] = f2bf(acc[mt][n2][rr]);
            }
    }
}

// ---------------------------------------------------------------------------
// Flash attention: single-wave blocks, K/V chunks (64 kv) double-buffered in
// LDS via global_load_lds. Per step: waitcnt(0) [drains loads issued a full
// step earlier] -> ds_read all frags -> issue stage(j+1) [LDS anti-dependence
// pins order] -> QK MFMA, online softmax (base-2), P-transpose shuffles, PV.
// 512 blocks longest-first = 2/CU; LDS 64KB.
// ---------------------------------------------------------------------------
__global__ __launch_bounds__(64, 1)
void attn_kernel(const unsigned short* __restrict__ qb,
                 const unsigned short* __restrict__ kb,
                 const unsigned short* __restrict__ vt,
                 float* __restrict__ out) {
    __shared__ __align__(16) char smem[65536];
    char* Kb = smem;            // 2 x 16KB : [64 kv][128 h] bf16
    char* Vb = smem + 32768;    // 2 x 16KB : [128 h][64 kv] bf16

    const int bx   = blockIdx.x;
    const int b    = bx & 3;
    const int tile = 127 - (bx >> 2);     // longest-first
    const int lane = threadIdx.x;
    const int p = lane >> 4, c = lane & 15;
    const int t0 = tile * 16;
    const int qg = t0 + c;
    const int u7 = c & 7;

    const unsigned short* kbat = kb + (size_t)b * CTX * HEAD;
    const unsigned short* vbat = vt + (size_t)b * HEAD * CTX;

    bf16x8 qf[4];
    #pragma unroll
    for (int ks = 0; ks < 4; ++ks)
        qf[ks] = *(const bf16x8*)&qb[((size_t)b * CTX + t0 + c) * HEAD + ks * 32 + p * 8];

    f32x4 o[8];
    #pragma unroll
    for (int i = 0; i < 8; ++i) o[i] = (f32x4){0.f, 0.f, 0.f, 0.f};
    float m = -FINF, l = 0.f;

    const int  slA = 32 * (p & 1) + c;
    const int  slB = slA + 16;
    const bool thi = (p >> 1) != 0;
    const int  nsteps = (tile + 4) >> 2;
    const float scale2 = 0.08838834764831845f * 1.44269504088896340f;  // 1/sqrt(128)*log2e

    auto stage = [&](int bi, int js) {
        const unsigned short* kg = kbat + (size_t)(js * 64) * HEAD;
        #pragma unroll
        for (int i = 0; i < 16; ++i) {     // K: 64 rows x 256B
            const int f = i * 64 + lane;
            const int r = f >> 4, s = f & 15, q = s ^ (r & 7);
            cp16(kg + (size_t)r * HEAD + q * 8, Kb + bi * 16384 + i * 1024);
        }
        #pragma unroll
        for (int i = 0; i < 16; ++i) {     // V: 128 rows x 128B
            const int f = i * 64 + lane;
            const int r = f >> 3, s = f & 7, q = s ^ (r & 7);
            cp16(vbat + (size_t)r * CTX + js * 64 + q * 8, Vb + bi * 16384 + i * 1024);
        }
    };

    stage(0, 0);
    for (int js = 0; js < nsteps; ++js) {
        const int cur = js & 1;
        __builtin_amdgcn_s_waitcnt(0);     // drain stage(js) (issued one step ago)

        // read all K/V fragments of this chunk from LDS first
        bf16x8 kfr[4][4], vfr[2][8];
        #pragma unroll
        for (int nt = 0; nt < 4; ++nt) {
            const char* rp = Kb + cur * 16384 + (nt * 16 + c) * 256;
            #pragma unroll
            for (int ks = 0; ks < 4; ++ks)
                kfr[nt][ks] = *(const bf16x8*)(rp + (((ks * 4 + p) ^ u7) * 16));
        }
        #pragma unroll
        for (int mt = 0; mt < 8; ++mt) {
            const char* rp = Vb + cur * 16384 + (mt * 16 + c) * 128;
            #pragma unroll
            for (int ch = 0; ch < 2; ++ch)
                vfr[ch][mt] = *(const bf16x8*)(rp + (((ch * 4 + p) ^ u7) * 16));
        }

        // prefetch next chunk (cannot be hoisted above the reads: same LDS array)
        if (js + 1 < nsteps) stage(cur ^ 1, js + 1);

        // S^T = K * Q^T
        const int c0 = js * 64;
        f32x4 st[4];
        #pragma unroll
        for (int nt = 0; nt < 4; ++nt) st[nt] = (f32x4){0.f, 0.f, 0.f, 0.f};
        #pragma unroll
        for (int ks = 0; ks < 4; ++ks)
            #pragma unroll
            for (int nt = 0; nt < 4; ++nt)
                st[nt] = __builtin_amdgcn_mfma_f32_16x16x32_bf16(kfr[nt][ks], qf[ks], st[nt], 0, 0, 0);

        float s[4][4];
        float lm = -FINF;
        if (js == nsteps - 1) {            // only the last step touches the diagonal
            #pragma unroll
            for (int nt = 0; nt < 4; ++nt)
                #pragma unroll
                for (int r = 0; r < 4; ++r) {
                    const int kv = c0 + nt * 16 + p * 4 + r;
                    float v = st[nt][r] * scale2;
                    v = (kv <= qg) ? v : -FINF;
                    s[nt][r] = v;
                    lm = fmaxf(lm, v);
                }
        } else {
            #pragma unroll
            for (int nt = 0; nt < 4; ++nt)
                #pragma unroll
                for (int r = 0; r < 4; ++r) {
                    const float v = st[nt][r] * scale2;
                    s[nt][r] = v;
                    lm = fmaxf(lm, v);
                }
        }
        lm = fmaxf(lm, __shfl_xor(lm, 16, 64));
        lm = fmaxf(lm, __shfl_xor(lm, 32, 64));
        const float m_new = fmaxf(m, lm);
        const float alpha = fexp2(m - m_new);
        float ls = 0.f;
        #pragma unroll
        for (int nt = 0; nt < 4; ++nt)
            #pragma unroll
            for (int r = 0; r < 4; ++r) {
                const float pv = fexp2(s[nt][r] - m_new);
                s[nt][r] = pv;
                ls += pv;
            }
        ls += __shfl_xor(ls, 16, 64);
        ls += __shfl_xor(ls, 32, 64);
        l = l * alpha + ls;
        m = m_new;
        #pragma unroll
        for (int i = 0; i < 8; ++i) {
            o[i][0] *= alpha; o[i][1] *= alpha;
            o[i][2] *= alpha; o[i][3] *= alpha;
        }
        // P^T B-frags via shuffles, then O^T += V^T * P^T
        #pragma unroll
        for (int ch = 0; ch < 2; ++ch) {
            const unsigned pa0 = pk2(s[2*ch][0],     s[2*ch][1]);
            const unsigned pb0 = pk2(s[2*ch][2],     s[2*ch][3]);
            const unsigned pa1 = pk2(s[2*ch + 1][0], s[2*ch + 1][1]);
            const unsigned pb1 = pk2(s[2*ch + 1][2], s[2*ch + 1][3]);
            const unsigned u0a = __shfl((int)pa0, slA, 64), u0b = __shfl((int)pa1, slA, 64);
            const unsigned u1a = __shfl((int)pb0, slA, 64), u1b = __shfl((int)pb1, slA, 64);
            const unsigned u2a = __shfl((int)pa0, slB, 64), u2b = __shfl((int)pa1, slB, 64);
            const unsigned u3a = __shfl((int)pb0, slB, 64), u3b = __shfl((int)pb1, slB, 64);
            union { unsigned u[4]; bf16x8 v; } pf;
            pf.u[0] = thi ? u0b : u0a;
            pf.u[1] = thi ? u1b : u1a;
            pf.u[2] = thi ? u2b : u2a;
            pf.u[3] = thi ? u3b : u3a;
            #pragma unroll
            for (int mt = 0; mt < 8; ++mt)
                o[mt] = __builtin_amdgcn_mfma_f32_16x16x32_bf16(vfr[ch][mt], pf.v, o[mt], 0, 0, 0);
        }
    }

    // O^T[h = mt*16+p*4+r][q = t0+c] / l  ->  out[b, t0+c, h]
    const float linv = 1.f / l;
    float* orow = out + ((size_t)b * CTX + t0 + c) * HEAD;
    #pragma unroll
    for (int mt = 0; mt < 8; ++mt) {
        float4 ov = make_float4(o[mt][0] * linv, o[mt][1] * linv,
                                o[mt][2] * linv, o[mt][3] * linv);
        *(float4*)&orow[mt * 16 + p * 4] = ov;
    }
}

// ---------------------------------------------------------------------------
extern "C" void kernel_launch(void* const* d_in, const int* in_sizes, int n_in,
                              void* d_out, int out_size, void* d_ws, size_t ws_size,
                              hipStream_t stream) {
    const float* x  = (const float*)d_in[0];
    const float* Wq = (const float*)d_in[1];
    const float* Wk = (const float*)d_in[2];
    const float* Wv = (const float*)d_in[3];
    float* out = (float*)d_out;

    unsigned short* Wt = (unsigned short*)d_ws;                 // 3*128*1024
    unsigned short* qb = Wt + (size_t)3 * HEAD * EMB;           // 8192*128
    unsigned short* kb = qb + (size_t)BATCH * CTX * HEAD;
    unsigned short* vt = kb + (size_t)BATCH * CTX * HEAD;

    transpose_w_kernel<<<dim3(16, 2, 3), 256, 0, stream>>>(Wq, Wk, Wv, Wt);
    proj_kernel<<<dim3((BATCH * CTX) / 32, 3), 128, 0, stream>>>(x, Wt, qb, kb, vt);
    attn_kernel<<<BATCH * (CTX / 16), 64, 0, stream>>>(qb, kb, vt, out);
}

// Round 7
// 125.951 us; speedup vs baseline: 6.6494x; 1.1591x over previous
//
#include <hip/hip_runtime.h>

#define BATCH 4
#define CTX   2048
#define EMB   1024
#define HEAD  128

typedef __attribute__((ext_vector_type(8))) short bf16x8;
typedef __attribute__((ext_vector_type(4))) float f32x4;
typedef const __attribute__((address_space(1))) unsigned int* gas_t;
typedef __attribute__((address_space(3))) unsigned int* las_t;

#define FINF (__builtin_inff())
__device__ inline float fexp2(float x) { return __builtin_amdgcn_exp2f(x); }

// async global->LDS, 16B per lane. LDS dest = wave-uniform base + lane*16.
__device__ inline void cp16(const void* g, void* l) {
    __builtin_amdgcn_global_load_lds((gas_t)g, (las_t)l, 16, 0, 0);
}

__device__ inline unsigned short f2bf(float f) {
    union { float f; unsigned u; } v; v.f = f;
    unsigned r = v.u + 0x7fffu + ((v.u >> 16) & 1u);
    return (unsigned short)(r >> 16);
}
__device__ inline unsigned pk2(float a, float b) {
    return (unsigned)f2bf(a) | ((unsigned)f2bf(b) << 16);
}
__device__ inline float bf2f(unsigned u16) {   // low 16 bits = bf16
    union { unsigned u; float f; } v; v.u = u16 << 16; return v.f;
}

// ---------------------------------------------------------------------------
// W[1024][128] fp32 -> Wt[w][128][1024] bf16 (transposed). grid (16,2,3).
// ---------------------------------------------------------------------------
__global__ __launch_bounds__(256)
void transpose_w_kernel(const float* __restrict__ Wq, const float* __restrict__ Wk,
                        const float* __restrict__ Wv, unsigned short* __restrict__ Wt) {
    const int k0 = blockIdx.x * 64;
    const int h0 = blockIdx.y * 64;
    const int w  = blockIdx.z;
    const float* W = (w == 0) ? Wq : (w == 1) ? Wk : Wv;
    __shared__ float Ts[64][65];
    const int tid = threadIdx.x;
    #pragma unroll
    for (int it = 0; it < 4; ++it) {
        const int kk = (tid >> 4) + it * 16;
        const int c4 = (tid & 15) * 4;
        const float4 f = *(const float4*)&W[(size_t)(k0 + kk) * HEAD + h0 + c4];
        Ts[kk][c4 + 0] = f.x; Ts[kk][c4 + 1] = f.y;
        Ts[kk][c4 + 2] = f.z; Ts[kk][c4 + 3] = f.w;
    }
    __syncthreads();
    const int hr  = tid >> 2;
    const int kc0 = (tid & 3) * 16;
    union { unsigned short s[16]; uint4 q[2]; } tmp;
    #pragma unroll
    for (int i = 0; i < 16; ++i) tmp.s[i] = f2bf(Ts[kc0 + i][hr]);
    unsigned short* dst = &Wt[(size_t)w * HEAD * EMB + (size_t)(h0 + hr) * EMB + k0 + kc0];
    ((uint4*)dst)[0] = tmp.q[0];
    ((uint4*)dst)[1] = tmp.q[1];
}

// ---------------------------------------------------------------------------
// QKV projection: LDS double-buffered MFMA GEMM (unchanged from R6).
// ---------------------------------------------------------------------------
__global__ __launch_bounds__(128, 3)
void proj_kernel(const float* __restrict__ x, const unsigned short* __restrict__ Wt,
                 unsigned short* __restrict__ qb, unsigned short* __restrict__ kb,
                 unsigned short* __restrict__ vt) {
    __shared__ __align__(16) char smem[24576];
    char* Ab = smem;            // 2 x 4KB : x tile [32 tok][32 k] fp32
    char* Bb = smem + 8192;     // 2 x 8KB : W tile [128 h][32 k] bf16

    const int wsel = blockIdx.y;
    const int tid  = threadIdx.x;
    const int wv   = tid >> 6;
    const int lane = tid & 63;
    const int p = lane >> 4, c = lane & 15;
    const int m0 = blockIdx.x * 32;
    const unsigned short* Wp = Wt + (size_t)wsel * HEAD * EMB;

    const int u7  = c & 7;
    const int u2c = (c ^ (c >> 2)) & 3;

    auto stage = [&](int bi, int ks) {
        #pragma unroll
        for (int i = 0; i < 2; ++i) {      // A: 32 rows x 128B
            const int f = i * 128 + tid;
            const int r = f >> 3, s = f & 7, q = s ^ (r & 7);
            cp16(&x[(size_t)(m0 + r) * EMB + ks * 32 + q * 4],
                 Ab + bi * 4096 + i * 2048 + wv * 1024);
        }
        #pragma unroll
        for (int i = 0; i < 4; ++i) {      // B: 128 rows x 64B
            const int f = i * 128 + tid;
            const int h = f >> 2, s = f & 3, q = s ^ ((h ^ (h >> 2)) & 3);
            cp16(&Wp[(size_t)h * EMB + ks * 32 + q * 8],
                 Bb + bi * 8192 + i * 2048 + wv * 1024);
        }
    };
    auto xfrag = [&](const char* Ac, int r) {
        const float4 a0 = *(const float4*)(Ac + r * 128 + (((2 * p)     ^ u7) * 16));
        const float4 a1 = *(const float4*)(Ac + r * 128 + (((2 * p + 1) ^ u7) * 16));
        union { unsigned u[4]; bf16x8 v; } xf;
        xf.u[0] = pk2(a0.x, a0.y); xf.u[1] = pk2(a0.z, a0.w);
        xf.u[2] = pk2(a1.x, a1.y); xf.u[3] = pk2(a1.z, a1.w);
        return xf.v;
    };

    if (wsel < 2) {
        f32x4 acc[8];
        #pragma unroll
        for (int i = 0; i < 8; ++i) acc[i] = (f32x4){0.f, 0.f, 0.f, 0.f};
        stage(0, 0);
        for (int ks = 0; ks < 32; ++ks) {
            const int cur = ks & 1;
            __syncthreads();
            if (ks + 1 < 32) stage(cur ^ 1, ks + 1);
            const bf16x8 xv = xfrag(Ab + cur * 4096, wv * 16 + c);
            const char* Bc = Bb + cur * 8192;
            #pragma unroll
            for (int nt = 0; nt < 8; ++nt) {
                const int h = nt * 16 + c;
                const bf16x8 wf = *(const bf16x8*)(Bc + h * 64 + ((p ^ u2c) * 16));
                acc[nt] = __builtin_amdgcn_mfma_f32_16x16x32_bf16(xv, wf, acc[nt], 0, 0, 0);
            }
        }
        unsigned short* outp = (wsel == 0) ? qb : kb;
        #pragma unroll
        for (int rr = 0; rr < 4; ++rr) {
            unsigned short* orow = outp + (size_t)(m0 + wv * 16 + p * 4 + rr) * HEAD + c;
            #pragma unroll
            for (int nt = 0; nt < 8; ++nt)
                orow[nt * 16] = f2bf(acc[nt][rr]);
        }
    } else {
        f32x4 acc[4][2];
        #pragma unroll
        for (int i = 0; i < 4; ++i)
            #pragma unroll
            for (int j = 0; j < 2; ++j) acc[i][j] = (f32x4){0.f, 0.f, 0.f, 0.f};
        stage(0, 0);
        for (int ks = 0; ks < 32; ++ks) {
            const int cur = ks & 1;
            __syncthreads();
            if (ks + 1 < 32) stage(cur ^ 1, ks + 1);
            const char* Ac = Ab + cur * 4096;
            const char* Bc = Bb + cur * 8192;
            bf16x8 xv[2];
            #pragma unroll
            for (int n2 = 0; n2 < 2; ++n2) xv[n2] = xfrag(Ac, n2 * 16 + c);
            #pragma unroll
            for (int mt = 0; mt < 4; ++mt) {
                const int h = wv * 64 + mt * 16 + c;
                const bf16x8 wf = *(const bf16x8*)(Bc + h * 64 + ((p ^ u2c) * 16));
                #pragma unroll
                for (int n2 = 0; n2 < 2; ++n2)
                    acc[mt][n2] = __builtin_amdgcn_mfma_f32_16x16x32_bf16(wf, xv[n2], acc[mt][n2], 0, 0, 0);
            }
        }
        const int bidx = m0 >> 11;
        const int tl   = m0 & (CTX - 1);
        unsigned short* vbp = vt + (size_t)bidx * HEAD * CTX;
        #pragma unroll
        for (int mt = 0; mt < 4; ++mt)
            #pragma unroll
            for (int rr = 0; rr < 4; ++rr) {
                const int h = wv * 64 + mt * 16 + p * 4 + rr;
                #pragma unroll
                for (int n2 = 0; n2 < 2; ++n2)
                    vbp[(size_t)h * CTX + tl + n2 * 16 + c] = f2bf(acc[mt][n2][rr]);
            }
    }
}

// ---------------------------------------------------------------------------
// Split-KV flash attention. Block = 256 threads (4 waves) = 64 q rows
// (wave w -> rows t0+16w..+15), one 512-kv chunk (<=8 steps of 64 kv).
// K/V staged via global_load_lds, double-buffered (64KB LDS), shared by all
// 4 waves. Partial (m,l,O bf16) -> workspace; merge kernel combines chunks.
// grid (80, 4): per batch, tile T (0..31) has T/8+1 chunks.
// ---------------------------------------------------------------------------
__global__ __launch_bounds__(256, 2)
void attn_split_kernel(const unsigned short* __restrict__ qb,
                       const unsigned short* __restrict__ kb,
                       const unsigned short* __restrict__ vt,
                       unsigned short* __restrict__ pO,
                       float* __restrict__ pM, float* __restrict__ pL) {
    __shared__ __align__(16) char smem[65536];
    char* Kb = smem;            // 2 x 16KB : [64 kv][128 h] bf16
    char* Vb = smem + 32768;    // 2 x 16KB : [128 h][64 kv] bf16

    const int g = blockIdx.x;   // 0..79
    const int b = blockIdx.y;
    int T, ch;
    if (g < 8)       { T = g;                ch = 0; }
    else if (g < 24) { T = 8  + ((g - 8) >> 1);  ch = (g - 8) & 1; }
    else if (g < 48) { T = 16 + (g - 24) / 3;    ch = (g - 24) % 3; }
    else             { T = 24 + ((g - 48) >> 2); ch = (g - 48) & 3; }
    const int nch    = (T >> 3) + 1;
    const int kstart = ch * 512;
    const int kend   = min(kstart + 512, 64 * (T + 1));
    const int nsteps = (kend - kstart) >> 6;
    const bool lastchunk = (ch == nch - 1);

    const int tid  = threadIdx.x;
    const int wv   = tid >> 6;
    const int lane = tid & 63;
    const int p = lane >> 4, c = lane & 15;
    const int t0 = T * 64;
    const int qg = t0 + wv * 16 + c;
    const int u7 = c & 7;

    const unsigned short* kbat = kb + (size_t)b * CTX * HEAD;
    const unsigned short* vbat = vt + (size_t)b * HEAD * CTX;

    bf16x8 qf[4];
    #pragma unroll
    for (int ks = 0; ks < 4; ++ks)
        qf[ks] = *(const bf16x8*)&qb[((size_t)b * CTX + t0 + wv * 16 + c) * HEAD + ks * 32 + p * 8];

    f32x4 o[8];
    #pragma unroll
    for (int i = 0; i < 8; ++i) o[i] = (f32x4){0.f, 0.f, 0.f, 0.f};
    float m = -FINF, l = 0.f;

    const int  slA = 32 * (p & 1) + c;
    const int  slB = slA + 16;
    const bool thi = (p >> 1) != 0;
    const float scale2 = 0.08838834764831845f * 1.44269504088896340f;  // 1/sqrt(128)*log2e

    auto stage = [&](int bi, int js) {
        const unsigned short* kg = kbat + (size_t)(kstart + js * 64) * HEAD;
        #pragma unroll
        for (int i = 0; i < 4; ++i) {      // K: 64 rows x 256B
            const int f = i * 256 + tid;
            const int r = f >> 4, s = f & 15, q = s ^ (r & 7);
            cp16(kg + (size_t)r * HEAD + q * 8, Kb + bi * 16384 + (f >> 6) * 1024);
        }
        const unsigned short* vg = vbat + kstart + js * 64;
        #pragma unroll
        for (int i = 0; i < 4; ++i) {      // V: 128 rows x 128B
            const int f = i * 256 + tid;
            const int r = f >> 3, s = f & 7, q = s ^ (r & 7);
            cp16(vg + (size_t)r * CTX + q * 8, Vb + bi * 16384 + (f >> 6) * 1024);
        }
    };

    stage(0, 0);
    for (int js = 0; js < nsteps; ++js) {
        const int cur = js & 1;
        __builtin_amdgcn_s_waitcnt(0);
        __syncthreads();                   // buf[cur] staged by all waves

        // K fragments for this step
        bf16x8 kfr[4][4];
        #pragma unroll
        for (int nt = 0; nt < 4; ++nt) {
            const char* rp = Kb + cur * 16384 + (nt * 16 + c) * 256;
            #pragma unroll
            for (int ks = 0; ks < 4; ++ks)
                kfr[nt][ks] = *(const bf16x8*)(rp + (((ks * 4 + p) ^ u7) * 16));
        }
        // prefetch next chunk into the other buffer
        if (js + 1 < nsteps) stage(cur ^ 1, js + 1);

        // S^T = K * Q^T
        f32x4 st[4];
        #pragma unroll
        for (int nt = 0; nt < 4; ++nt) st[nt] = (f32x4){0.f, 0.f, 0.f, 0.f};
        #pragma unroll
        for (int ks = 0; ks < 4; ++ks)
            #pragma unroll
            for (int nt = 0; nt < 4; ++nt)
                st[nt] = __builtin_amdgcn_mfma_f32_16x16x32_bf16(kfr[nt][ks], qf[ks], st[nt], 0, 0, 0);

        // V fragments (other LDS region; reads overlap softmax)
        bf16x8 vfr[2][8];
        #pragma unroll
        for (int mt = 0; mt < 8; ++mt) {
            const char* rp = Vb + cur * 16384 + (mt * 16 + c) * 128;
            #pragma unroll
            for (int ch2 = 0; ch2 < 2; ++ch2)
                vfr[ch2][mt] = *(const bf16x8*)(rp + (((ch2 * 4 + p) ^ u7) * 16));
        }

        float s[4][4];
        float lm = -FINF;
        if (lastchunk && js == nsteps - 1) {
            #pragma unroll
            for (int nt = 0; nt < 4; ++nt)
                #pragma unroll
                for (int r = 0; r < 4; ++r) {
                    const int kv = kstart + js * 64 + nt * 16 + p * 4 + r;
                    float v = st[nt][r] * scale2;
                    v = (kv <= qg) ? v : -FINF;
                    s[nt][r] = v;
                    lm = fmaxf(lm, v);
                }
        } else {
            #pragma unroll
            for (int nt = 0; nt < 4; ++nt)
                #pragma unroll
                for (int r = 0; r < 4; ++r) {
                    const float v = st[nt][r] * scale2;
                    s[nt][r] = v;
                    lm = fmaxf(lm, v);
                }
        }
        lm = fmaxf(lm, __shfl_xor(lm, 16, 64));
        lm = fmaxf(lm, __shfl_xor(lm, 32, 64));
        const float m_new = fmaxf(m, lm);
        const float alpha = fexp2(m - m_new);
        float ls = 0.f;
        #pragma unroll
        for (int nt = 0; nt < 4; ++nt)
            #pragma unroll
            for (int r = 0; r < 4; ++r) {
                const float pv = fexp2(s[nt][r] - m_new);
                s[nt][r] = pv;
                ls += pv;
            }
        ls += __shfl_xor(ls, 16, 64);
        ls += __shfl_xor(ls, 32, 64);
        l = l * alpha + ls;
        m = m_new;
        #pragma unroll
        for (int i = 0; i < 8; ++i) {
            o[i][0] *= alpha; o[i][1] *= alpha;
            o[i][2] *= alpha; o[i][3] *= alpha;
        }
        // P^T B-frags via shuffles, then O^T += V^T * P^T
        #pragma unroll
        for (int ch2 = 0; ch2 < 2; ++ch2) {
            const unsigned pa0 = pk2(s[2*ch2][0],     s[2*ch2][1]);
            const unsigned pb0 = pk2(s[2*ch2][2],     s[2*ch2][3]);
            const unsigned pa1 = pk2(s[2*ch2 + 1][0], s[2*ch2 + 1][1]);
            const unsigned pb1 = pk2(s[2*ch2 + 1][2], s[2*ch2 + 1][3]);
            const unsigned u0a = __shfl((int)pa0, slA, 64), u0b = __shfl((int)pa1, slA, 64);
            const unsigned u1a = __shfl((int)pb0, slA, 64), u1b = __shfl((int)pb1, slA, 64);
            const unsigned u2a = __shfl((int)pa0, slB, 64), u2b = __shfl((int)pa1, slB, 64);
            const unsigned u3a = __shfl((int)pb0, slB, 64), u3b = __shfl((int)pb1, slB, 64);
            union { unsigned u[4]; bf16x8 v; } pf;
            pf.u[0] = thi ? u0b : u0a;
            pf.u[1] = thi ? u1b : u1a;
            pf.u[2] = thi ? u2b : u2a;
            pf.u[3] = thi ? u3b : u3a;
            #pragma unroll
            for (int mt = 0; mt < 8; ++mt)
                o[mt] = __builtin_amdgcn_mfma_f32_16x16x32_bf16(vfr[ch2][mt], pf.v, o[mt], 0, 0, 0);
        }
    }

    // partial store: O^T[h=mt*16+p*4+r][q=wv*16+c] -> pO[chunk][qlocal][h] bf16
    const size_t pbase = (size_t)(b * 32 + T) * 4 + ch;
    unsigned short* po = pO + pbase * (64 * 128) + (wv * 16 + c) * 128;
    #pragma unroll
    for (int mt = 0; mt < 8; ++mt) {
        union { unsigned short sh[4]; uint2 u; } t;
        #pragma unroll
        for (int r = 0; r < 4; ++r) t.sh[r] = f2bf(o[mt][r]);
        *(uint2*)&po[mt * 16 + p * 4] = t.u;
    }
    if (p == 0) {
        pM[pbase * 64 + wv * 16 + c] = m;
        pL[pbase * 64 + wv * 16 + c] = l;
    }
}

// ---------------------------------------------------------------------------
// Merge partial chunks: out = sum_i w_i O_i / sum_i w_i l_i, w_i = 2^(m_i-M).
// grid (32, 4), 256 threads: thread -> (row = tid>>2, 32 cols).
// ---------------------------------------------------------------------------
__global__ __launch_bounds__(256)
void attn_merge_kernel(const unsigned short* __restrict__ pO,
                       const float* __restrict__ pM, const float* __restrict__ pL,
                       float* __restrict__ out) {
    const int T = blockIdx.x, b = blockIdx.y;
    const int nch = (T >> 3) + 1;
    const int tid = threadIdx.x;
    const int r   = tid >> 2;
    const int c0  = (tid & 3) * 32;
    const size_t base = (size_t)(b * 32 + T) * 4;

    float mv[4], lv[4];
    float M = -FINF;
    #pragma unroll
    for (int i = 0; i < 4; ++i) {
        if (i < nch) { mv[i] = pM[(base + i) * 64 + r]; lv[i] = pL[(base + i) * 64 + r]; }
        else         { mv[i] = -FINF;                   lv[i] = 0.f; }
        M = fmaxf(M, mv[i]);
    }
    float w[4], L = 0.f;
    #pragma unroll
    for (int i = 0; i < 4; ++i) { w[i] = fexp2(mv[i] - M); L += w[i] * lv[i]; }
    const float inv = 1.f / L;

    float acc[32];
    #pragma unroll
    for (int j = 0; j < 32; ++j) acc[j] = 0.f;
    #pragma unroll
    for (int i = 0; i < 4; ++i) {
        if (i < nch) {                        // nch uniform per block: no divergence
            const unsigned* s32 = (const unsigned*)(pO + (base + i) * (64 * 128) + r * 128 + c0);
            const float wi = w[i];
            #pragma unroll
            for (int jw = 0; jw < 16; ++jw) {
                const unsigned u = s32[jw];
                acc[2 * jw]     += wi * bf2f(u & 0xffffu);
                acc[2 * jw + 1] += wi * bf2f(u >> 16);
            }
        }
    }
    float* orow = out + ((size_t)b * CTX + T * 64 + r) * HEAD + c0;
    #pragma unroll
    for (int j4 = 0; j4 < 8; ++j4) {
        float4 ov = make_float4(acc[4*j4] * inv, acc[4*j4+1] * inv,
                                acc[4*j4+2] * inv, acc[4*j4+3] * inv);
        *(float4*)&orow[4 * j4] = ov;
    }
}

// ---------------------------------------------------------------------------
// Fallback attention (R6): single-wave blocks, used if ws too small for split.
// ---------------------------------------------------------------------------
__global__ __launch_bounds__(64, 1)
void attn_kernel(const unsigned short* __restrict__ qb,
                 const unsigned short* __restrict__ kb,
                 const unsigned short* __restrict__ vt,
                 float* __restrict__ out) {
    __shared__ __align__(16) char smem[65536];
    char* Kb = smem;
    char* Vb = smem + 32768;
    const int bx   = blockIdx.x;
    const int b    = bx & 3;
    const int tile = 127 - (bx >> 2);
    const int lane = threadIdx.x;
    const int p = lane >> 4, c = lane & 15;
    const int t0 = tile * 16;
    const int qg = t0 + c;
    const int u7 = c & 7;
    const unsigned short* kbat = kb + (size_t)b * CTX * HEAD;
    const unsigned short* vbat = vt + (size_t)b * HEAD * CTX;
    bf16x8 qf[4];
    #pragma unroll
    for (int ks = 0; ks < 4; ++ks)
        qf[ks] = *(const bf16x8*)&qb[((size_t)b * CTX + t0 + c) * HEAD + ks * 32 + p * 8];
    f32x4 o[8];
    #pragma unroll
    for (int i = 0; i < 8; ++i) o[i] = (f32x4){0.f, 0.f, 0.f, 0.f};
    float m = -FINF, l = 0.f;
    const int  slA = 32 * (p & 1) + c;
    const int  slB = slA + 16;
    const bool thi = (p >> 1) != 0;
    const int  nsteps = (tile + 4) >> 2;
    const float scale2 = 0.08838834764831845f * 1.44269504088896340f;
    auto stage = [&](int bi, int js) {
        const unsigned short* kg = kbat + (size_t)(js * 64) * HEAD;
        #pragma unroll
        for (int i = 0; i < 16; ++i) {
            const int f = i * 64 + lane;
            const int r = f >> 4, s = f & 15, q = s ^ (r & 7);
            cp16(kg + (size_t)r * HEAD + q * 8, Kb + bi * 16384 + i * 1024);
        }
        #pragma unroll
        for (int i = 0; i < 16; ++i) {
            const int f = i * 64 + lane;
            const int r = f >> 3, s = f & 7, q = s ^ (r & 7);
            cp16(vbat + (size_t)r * CTX + js * 64 + q * 8, Vb + bi * 16384 + i * 1024);
        }
    };
    stage(0, 0);
    for (int js = 0; js < nsteps; ++js) {
        const int cur = js & 1;
        __builtin_amdgcn_s_waitcnt(0);
        bf16x8 kfr[4][4], vfr[2][8];
        #pragma unroll
        for (int nt = 0; nt < 4; ++nt) {
            const char* rp = Kb + cur * 16384 + (nt * 16 + c) * 256;
            #pragma unroll
            for (int ks = 0; ks < 4; ++ks)
                kfr[nt][ks] = *(const bf16x8*)(rp + (((ks * 4 + p) ^ u7) * 16));
        }
        #pragma unroll
        for (int mt = 0; mt < 8; ++mt) {
            const char* rp = Vb + cur * 16384 + (mt * 16 + c) * 128;
            #pragma unroll
            for (int ch = 0; ch < 2; ++ch)
                vfr[ch][mt] = *(const bf16x8*)(rp + (((ch * 4 + p) ^ u7) * 16));
        }
        if (js + 1 < nsteps) stage(cur ^ 1, js + 1);
        const int c0 = js * 64;
        f32x4 st[4];
        #pragma unroll
        for (int nt = 0; nt < 4; ++nt) st[nt] = (f32x4){0.f, 0.f, 0.f, 0.f};
        #pragma unroll
        for (int ks = 0; ks < 4; ++ks)
            #pragma unroll
            for (int nt = 0; nt < 4; ++nt)
                st[nt] = __builtin_amdgcn_mfma_f32_16x16x32_bf16(kfr[nt][ks], qf[ks], st[nt], 0, 0, 0);
        float s[4][4];
        float lm = -FINF;
        if (js == nsteps - 1) {
            #pragma unroll
            for (int nt = 0; nt < 4; ++nt)
                #pragma unroll
                for (int r = 0; r < 4; ++r) {
                    const int kv = c0 + nt * 16 + p * 4 + r;
                    float v = st[nt][r] * scale2;
                    v = (kv <= qg) ? v : -FINF;
                    s[nt][r] = v;
                    lm = fmaxf(lm, v);
                }
        } else {
            #pragma unroll
            for (int nt = 0; nt < 4; ++nt)
                #pragma unroll
                for (int r = 0; r < 4; ++r) {
                    const float v = st[nt][r] * scale2;
                    s[nt][r] = v;
                    lm = fmaxf(lm, v);
                }
        }
        lm = fmaxf(lm, __shfl_xor(lm, 16, 64));
        lm = fmaxf(lm, __shfl_xor(lm, 32, 64));
        const float m_new = fmaxf(m, lm);
        const float alpha = fexp2(m - m_new);
        float ls = 0.f;
        #pragma unroll
        for (int nt = 0; nt < 4; ++nt)
            #pragma unroll
            for (int r = 0; r < 4; ++r) {
                const float pv = fexp2(s[nt][r] - m_new);
                s[nt][r] = pv;
                ls += pv;
            }
        ls += __shfl_xor(ls, 16, 64);
        ls += __shfl_xor(ls, 32, 64);
        l = l * alpha + ls;
        m = m_new;
        #pragma unroll
        for (int i = 0; i < 8; ++i) {
            o[i][0] *= alpha; o[i][1] *= alpha;
            o[i][2] *= alpha; o[i][3] *= alpha;
        }
        #pragma unroll
        for (int ch = 0; ch < 2; ++ch) {
            const unsigned pa0 = pk2(s[2*ch][0],     s[2*ch][1]);
            const unsigned pb0 = pk2(s[2*ch][2],     s[2*ch][3]);
            const unsigned pa1 = pk2(s[2*ch + 1][0], s[2*ch + 1][1]);
            const unsigned pb1 = pk2(s[2*ch + 1][2], s[2*ch + 1][3]);
            const unsigned u0a = __shfl((int)pa0, slA, 64), u0b = __shfl((int)pa1, slA, 64);
            const unsigned u1a = __shfl((int)pb0, slA, 64), u1b = __shfl((int)pb1, slA, 64);
            const unsigned u2a = __shfl((int)pa0, slB, 64), u2b = __shfl((int)pa1, slB, 64);
            const unsigned u3a = __shfl((int)pb0, slB, 64), u3b = __shfl((int)pb1, slB, 64);
            union { unsigned u[4]; bf16x8 v; } pf;
            pf.u[0] = thi ? u0b : u0a;
            pf.u[1] = thi ? u1b : u1a;
            pf.u[2] = thi ? u2b : u2a;
            pf.u[3] = thi ? u3b : u3a;
            #pragma unroll
            for (int mt = 0; mt < 8; ++mt)
                o[mt] = __builtin_amdgcn_mfma_f32_16x16x32_bf16(vfr[ch][mt], pf.v, o[mt], 0, 0, 0);
        }
    }
    const float linv = 1.f / l;
    float* orow = out + ((size_t)b * CTX + t0 + c) * HEAD;
    #pragma unroll
    for (int mt = 0; mt < 8; ++mt) {
        float4 ov = make_float4(o[mt][0] * linv, o[mt][1] * linv,
                                o[mt][2] * linv, o[mt][3] * linv);
        *(float4*)&orow[mt * 16 + p * 4] = ov;
    }
}

// ---------------------------------------------------------------------------
extern "C" void kernel_launch(void* const* d_in, const int* in_sizes, int n_in,
                              void* d_out, int out_size, void* d_ws, size_t ws_size,
                              hipStream_t stream) {
    const float* x  = (const float*)d_in[0];
    const float* Wq = (const float*)d_in[1];
    const float* Wk = (const float*)d_in[2];
    const float* Wv = (const float*)d_in[3];
    float* out = (float*)d_out;

    unsigned short* Wt = (unsigned short*)d_ws;                 // 3*128*1024
    unsigned short* qb = Wt + (size_t)3 * HEAD * EMB;           // 8192*128
    unsigned short* kb = qb + (size_t)BATCH * CTX * HEAD;
    unsigned short* vt = kb + (size_t)BATCH * CTX * HEAD;
    unsigned short* pO = vt + (size_t)BATCH * CTX * HEAD;       // 4*32*4*64*128 bf16
    float* pM = (float*)(pO + (size_t)BATCH * 32 * 4 * 64 * 128);
    float* pL = pM + (size_t)BATCH * 32 * 4 * 64;

    const size_t need = (size_t)((char*)(pL + BATCH * 32 * 4 * 64) - (char*)d_ws);

    transpose_w_kernel<<<dim3(16, 2, 3), 256, 0, stream>>>(Wq, Wk, Wv, Wt);
    proj_kernel<<<dim3((BATCH * CTX) / 32, 3), 128, 0, stream>>>(x, Wt, qb, kb, vt);
    if (ws_size >= need) {
        attn_split_kernel<<<dim3(80, 4), 256, 0, stream>>>(qb, kb, vt, pO, pM, pL);
        attn_merge_kernel<<<dim3(32, 4), 256, 0, stream>>>(pO, pM, pL, out);
    } else {
        attn_kernel<<<BATCH * (CTX / 16), 64, 0, stream>>>(qb, kb, vt, out);
    }
}